// Round 7
// baseline (441.165 us; speedup 1.0000x reference)
//
#include <hip/hip_runtime.h>
#include <type_traits>

#define N_ATOMS 256
#define N_MOL 4
#define N_PAIRS 8192
#define KE_C 14.3996
#define ALPHA_C 0.3
#define CUTOFF_C 6.0

#define KS_B 1344   // 84 k-pairs x 16 i-chunks
#define RE_B 400    // 25 cells x 16 i-chunks
#define BO_B 32     // 8192 pairs / 256
#define S2_B 8      // 8 j-chunks of 32
#define NBLK (KS_B+RE_B+BO_B+S2_B)
#define NCPY 32

constexpr double PI_D    = 3.14159265358979323846;
constexpr double TWOSQPI = 1.12837916709551257390; // 2/sqrt(pi)
#define AL_F 0.3f
#define TWOSQPI_F 1.12837917f
#define K1_F 0.33851375f    // TWOSQPI*ALPHA
#define IAS_F 1.8806320f    // 1/(ALPHA*sqrt(pi))

// ---------------- fast fp32 erfc (rel err ~1e-6 with __expf) ----------------
__device__ __forceinline__ float fast_erfcf(float x){
  float ax = fabsf(x);
  float t = __fdividef(1.0f, fmaf(0.5f, ax, 1.0f));
  float p = 0.17087277f;
  p = fmaf(p, t, -0.82215223f);
  p = fmaf(p, t,  1.48851587f);
  p = fmaf(p, t, -1.13520398f);
  p = fmaf(p, t,  0.27886807f);
  p = fmaf(p, t, -0.18628806f);
  p = fmaf(p, t,  0.09678418f);
  p = fmaf(p, t,  0.37409196f);
  p = fmaf(p, t,  1.00002368f);
  p = fmaf(p, t, -1.26551223f);
  float ans = t*__expf(fmaf(-ax, ax, p));
  return x >= 0.0f ? ans : 2.0f - ans;
}

// ---------------- dual numbers (fp64, Born HVP) -----------------------------
struct Dd {
  double v, t;
  __device__ Dd() {}
  __device__ Dd(double v_) : v(v_), t(0.0) {}
  __device__ Dd(double v_, double t_) : v(v_), t(t_) {}
};
__device__ inline Dd operator+(Dd a, Dd b){ return Dd(a.v+b.v, a.t+b.t); }
__device__ inline Dd operator+(Dd a, double b){ return Dd(a.v+b, a.t); }
__device__ inline Dd operator-(Dd a, Dd b){ return Dd(a.v-b.v, a.t-b.t); }
__device__ inline Dd operator*(Dd a, Dd b){ return Dd(a.v*b.v, a.t*b.v + a.v*b.t); }
__device__ inline Dd operator*(double a, Dd b){ return Dd(a*b.v, a*b.t); }
__device__ inline double fsqrt(double a){ return sqrt(a); }
__device__ inline Dd     fsqrt(Dd a){ double s=sqrt(a.v); return Dd(s, a.t*0.5/s); }
__device__ inline double finv(double a){ return 1.0/a; }
__device__ inline Dd     finv(Dd a){ double iv=1.0/a.v; return Dd(iv, -a.t*iv*iv); }
__device__ inline double ipown(double x, int e){
  double r = 1.0;
  while (e){ if (e & 1) r *= x; x *= x; e >>= 1; }
  return r;
}
__device__ inline double fpowni(double a, int n){ return ipown(1.0/a, n); }
__device__ inline Dd     fpowni(Dd a, int n){
  double iv = 1.0/a.v; double p = ipown(iv, n);
  return Dd(p, -(double)n*p*iv*a.t);
}
__device__ inline double gval(double a){ return a; }
__device__ inline double gval(Dd a){ return a.v; }
__device__ inline double pick(double a){ return a; }
__device__ inline double pick(Dd a){ return a.t; }
template<class T> __device__ inline T mk(double v, double t){
  if constexpr (std::is_same<T,double>::value) return v; else return Dd(v, t);
}

__device__ inline double cell_area(const float* cell){
  double a0=cell[0], a1=cell[1], a2=cell[2];
  double b0=cell[3], b1=cell[4], b2=cell[5];
  double cx=a1*b2-a2*b1, cy=a2*b0-a0*b2, cz=a0*b1-a1*b0;
  return sqrt(cx*cx+cy*cy+cz*cz);
}
// Rs[a][c] = R + film*shift[mol]
__device__ inline double posc(const float* R, const float* shiftv, const int* im,
                              const int* film, int a, int c){
  double mask = film[a] > 0 ? 1.0 : 0.0;
  return (double)R[a*3+c] + mask*(double)shiftv[im[a]*3+c];
}

// ---------------- pass kernel (P2=0: grad+energies; P2=1: HVP) --------------
// Last block to finish performs the reduction/epilogue (finish1 / finish2).
template<int P2>
__global__ __launch_bounds__(256) void pass_kernel(
    const float* R, const float* shiftv, const float* q, const float* offs,
    const float* cell, const float* recipc, const float* r0a, const float* na,
    const int* ii, const int* jj, const int* im, const int* film,
    double* V, double* gbase, double* scal, int* done, float* out){
  __shared__ double shd[1024];   // 8 KB, aliased float staging / finish scratch
  __shared__ double red[16];
  __shared__ int amLast;
  float* f = (float*)shd;
  int b = blockIdx.x, tid = threadIdx.x;

  if (b < KS_B) {
    // ================= k-space: kk = b>>4, i-chunk ic = b&15 ================
    int kk = b >> 4, ic = b & 15;
    double* g = gbase + ((kk + 2*ic) & (NCPY-1))*768;
    double b0 = (double)(kk/13 - 6), b1d = (double)(kk%13 - 6);
    double TP = 2.0*PI_D;
    double h0d = TP*(b0*(double)recipc[0] + b1d*(double)recipc[3]);
    double h1d = TP*(b0*(double)recipc[1] + b1d*(double)recipc[4]);
    double h2d = TP*(b0*(double)recipc[2] + b1d*(double)recipc[5]);
    double kapd = sqrt(h0d*h0d + h1d*h1d + h2d*h2d);
    float A    = (float)(kapd/(2.0*ALPHA_C));
    float ikap = (float)(1.0/kapd);
    float kapf = (float)kapd;
    {   // stage all 256 atoms' per-k entries (each thread computes one atom)
      int a = tid;
      double xa = posc(R,shiftv,im,film,a,0);
      double ya = posc(R,shiftv,im,film,a,1);
      double za = posc(R,shiftv,im,film,a,2);
      double phi = h0d*xa + h1d*ya + h2d*za;
      double s, c; sincos(phi, &s, &c);
      double E = exp(kapd*za);
      f[a]      = (float)c;       f[256+a]  = (float)s;
      f[512+a]  = (float)E;       f[768+a]  = (float)(1.0/E);
      f[1024+a] = (float)za;      f[1280+a] = q[a];
      if constexpr (P2) {
        f[1536+a] = (float)(h0d*V[a*3+0] + h1d*V[a*3+1] + h2d*V[a*3+2]);
        f[1792+a] = (float)V[a*3+2];
      }
    }
    __syncthreads();
    int il = tid >> 4, jl = tid & 15;
    int i = ic*16 + il;
    float ci=f[i], si=f[256+i], Ei=f[512+i], iEi=f[768+i];
    float zi=f[1024+i], qi=f[1280+i];
    float dpi=0.f, vzi=0.f;
    if constexpr (P2) { dpi = f[1536+i]; vzi = f[1792+i]; }
    double Sp=0.0, cmS=0.0, czS=0.0;
    #pragma unroll 4
    for (int t=0;t<16;++t){
      int j = t*16 + jl;
      float z  = zi - f[1024+j];
      float az = AL_F*z;
      float u1 = A + az, u2 = A - az;
      float ec1 = fast_erfcf(u1), ec2 = fast_erfcf(u2);
      float ekz = Ei*f[768+j], ikz = iEi*f[512+j];
      float e1 = ekz*ec1, e2 = ikz*ec2;
      float cj = f[j], sj = f[256+j];
      float cph = ci*cj + si*sj;
      float sph = si*cj - ci*sj;
      float fF  = (e1+e2)*ikap;
      float qq  = qi*f[1280+j];
      if constexpr (!P2) {
        Sp  += (double)(qq*cph*fF);
        cmS += (double)(-2.0f*qq*sph*fF);
        czS += (double)( 2.0f*qq*cph*(e1-e2));
      } else {
        float dz   = vzi - f[1792+j];
        float dphi = dpi - f[1536+j];
        float g1 = TWOSQPI_F*__expf(-u1*u1);
        float g2 = TWOSQPI_F*__expf(-u2*u2);
        float de1 = dz*(kapf*e1 - AL_F*ekz*g1);
        float de2 = dz*(AL_F*ikz*g2 - kapf*e2);
        float dF  = (de1+de2)*ikap;
        float dcs = -sph*dphi, dsn = cph*dphi;
        cmS += (double)(-2.0f*qq*(dsn*fF + sph*dF));
        czS += (double)( 2.0f*qq*(dcs*(e1-e2) + cph*(de1-de2)));
      }
    }
    #pragma unroll
    for (int m=1;m<16;m<<=1){
      cmS += __shfl_xor(cmS, m);
      czS += __shfl_xor(czS, m);
      if constexpr (!P2) Sp += __shfl_xor(Sp, m);
    }
    if (jl == 0){
      double gsc = 4.0*KE_C*PI_D/cell_area(cell);   // x4 mol, x2 +-k fold
      atomicAdd(&g[i*3+0], gsc*(h0d*cmS));
      atomicAdd(&g[i*3+1], gsc*(h1d*cmS));
      atomicAdd(&g[i*3+2], gsc*(h2d*cmS + czS));
      if constexpr (!P2) red[il] = Sp;
    }
    if constexpr (!P2){
      __syncthreads();
      if (tid == 0){
        double s = 0.0;
        #pragma unroll
        for (int u=0;u<16;++u) s += red[u];
        atomicAdd(&scal[((kk + 2*ic) & (NCPY-1))*8+0], 2.0*s);
      }
    }
  } else if (b < KS_B + RE_B) {
    // ================= real space: nn = r>>4, i-chunk = r&15 ================
    int r = b - KS_B; int nn = r >> 4, ic = r & 15;
    double* g = gbase + ((nn + 2*ic) & (NCPY-1))*768;
    double n0 = (double)(nn/5 - 2), n1 = (double)(nn%5 - 2);
    float a0 = (float)(n0*(double)cell[0] + n1*(double)cell[3]);
    float a1 = (float)(n0*(double)cell[1] + n1*(double)cell[4]);
    float a2 = (float)(n0*(double)cell[2] + n1*(double)cell[5]);
    {
      int a = tid;
      f[a]      = (float)posc(R,shiftv,im,film,a,0);
      f[256+a]  = (float)posc(R,shiftv,im,film,a,1);
      f[512+a]  = (float)posc(R,shiftv,im,film,a,2);
      f[768+a]  = q[a];
      if constexpr (P2) {
        f[1024+a]=(float)V[a*3+0]; f[1280+a]=(float)V[a*3+1]; f[1536+a]=(float)V[a*3+2];
      }
    }
    __syncthreads();
    int il = tid >> 4, jl = tid & 15;
    int i = ic*16 + il;
    float xi=f[i], yi=f[256+i], zi=f[512+i], qi=f[768+i];
    float vxi=0.f, vyi=0.f, vzi=0.f;
    if constexpr (P2){ vxi=f[1024+i]; vyi=f[1280+i]; vzi=f[1536+i]; }
    double gx=0,gy=0,gz=0,Rp=0;
    #pragma unroll 4
    for (int t=0;t<16;++t){
      int j = t*16 + jl;
      float rx = xi - f[j]     + a0;
      float ry = yi - f[256+j] + a1;
      float rz = zi - f[512+j] + a2;
      float dsq = rx*rx+ry*ry+rz*rz;
      if (dsq > 0.0f){
        float d = sqrtf(dsq);
        float invd = __fdividef(1.0f, d);
        float ad = AL_F*d;
        float ec = fast_erfcf(ad);
        float ex = __expf(-ad*ad);
        float qq = qi*f[768+j];
        float P  = -(K1_F*ex*invd + ec*invd*invd);
        float C  = qq*P*invd;
        if constexpr (!P2) {
          Rp += (double)(qq*ec*invd);
          gx += (double)(C*rx); gy += (double)(C*ry); gz += (double)(C*rz);
        } else {
          float drx = vxi - f[1024+j], dry = vyi - f[1280+j], drz = vzi - f[1536+j];
          float dd  = (rx*drx + ry*dry + rz*drz)*invd;
          float invd2 = invd*invd;
          float dC = qq*dd*( K1_F*ex*(2.0f*AL_F*AL_F + 3.0f*invd2)*invd
                             + 3.0f*ec*invd2*invd2 );
          gx += (double)(dC*rx + C*drx);
          gy += (double)(dC*ry + C*dry);
          gz += (double)(dC*rz + C*drz);
        }
      }
    }
    #pragma unroll
    for (int m=1;m<16;m<<=1){
      gx += __shfl_xor(gx, m); gy += __shfl_xor(gy, m); gz += __shfl_xor(gz, m);
      if constexpr (!P2) Rp += __shfl_xor(Rp, m);
    }
    if (jl == 0){
      atomicAdd(&g[i*3+0], 4.0*KE_C*gx);
      atomicAdd(&g[i*3+1], 4.0*KE_C*gy);
      atomicAdd(&g[i*3+2], 4.0*KE_C*gz);
      if constexpr (!P2) red[il] = Rp;
    }
    if constexpr (!P2){
      __syncthreads();
      if (tid == 0){
        double s = 0.0;
        #pragma unroll
        for (int u=0;u<16;++u) s += red[u];
        atomicAdd(&scal[((nn + 2*ic) & (NCPY-1))*8+2], s);
      }
    }
  } else if (b < KS_B + RE_B + BO_B) {
    // ================= Born (fp64 / dual), integer pow ======================
    using T = typename std::conditional<P2, Dd, double>::type;
    int bb = b - KS_B - RE_B;
    double* g = gbase + (bb & (NCPY-1))*768;
    int p = bb*256 + tid;
    int ai = ii[p], aj = jj[p];
    double pix = posc(R,shiftv,im,film,ai,0), pjx = posc(R,shiftv,im,film,aj,0);
    double piy = posc(R,shiftv,im,film,ai,1), pjy = posc(R,shiftv,im,film,aj,1);
    double piz = posc(R,shiftv,im,film,ai,2), pjz = posc(R,shiftv,im,film,aj,2);
    double tx=0.0, ty=0.0, tz=0.0;
    if constexpr (P2){
      tx = V[aj*3+0]-V[ai*3+0];
      ty = V[aj*3+1]-V[ai*3+1];
      tz = V[aj*3+2]-V[ai*3+2];
    }
    T rx = mk<T>(pjx-pix+(double)offs[p*3+0], tx);
    T ry = mk<T>(pjy-piy+(double)offs[p*3+1], ty);
    T rz = mk<T>(pjz-piz+(double)offs[p*3+2], tz);
    T dsq = rx*rx + ry*ry + rz*rz;
    T d = fsqrt(dsq);
    double y = 0.0;
    if (gval(d) < CUTOFF_C) {
      double qq = fabs((double)q[ai]*(double)q[aj]);
      int    ni = (int)(na[p] + 0.5f);
      double n  = (double)ni;
      double B  = qq * ipown((double)r0a[p], ni-1) / n;
      T dmn = fpowni(d, ni);
      if constexpr (!P2)
        y = 0.5*KE_C*B*(gval(dmn) - ipown(1.0/CUTOFF_C, ni));
      T c = (-0.5*KE_C*n*B) * (dmn * finv(dsq));
      T fx = c*rx, fy = c*ry, fz = c*rz;
      atomicAdd(&g[aj*3+0],  pick(fx));
      atomicAdd(&g[aj*3+1],  pick(fy));
      atomicAdd(&g[aj*3+2],  pick(fz));
      atomicAdd(&g[ai*3+0], -pick(fx));
      atomicAdd(&g[ai*3+1], -pick(fy));
      atomicAdd(&g[ai*3+2], -pick(fz));
    }
    if constexpr (!P2) {
      int myMol = im[ai];
      #pragma unroll
      for (int mm=0; mm<4; ++mm){
        double v = (myMol==mm) ? y : 0.0;
        for (int off=32; off; off>>=1) v += __shfl_down(v, off, 64);
        if ((tid & 63) == 0 && v != 0.0)
          atomicAdd(&scal[(bb & (NCPY-1))*8+3+mm], v);
      }
    }
  } else {
    // ================= S2 (fp32): i = tid, 32-j chunk =======================
    int jc = b - (KS_B + RE_B + BO_B);
    double* g = gbase + ((jc*4) & (NCPY-1))*768;
    if (tid < 32) {
      int j = jc*32 + tid;
      f[tid]    = (float)posc(R,shiftv,im,film,j,2);
      f[32+tid] = q[j];
      f[64+tid] = P2 ? (float)V[j*3+2] : 0.0f;
    }
    __syncthreads();
    float ziv = (float)posc(R,shiftv,im,film,tid,2), qi = q[tid];
    float vzi = 0.0f;
    if constexpr (P2) vzi = (float)V[tid*3+2];
    double acc = 0.0, S2p = 0.0;
    for (int j2=0;j2<32;++j2){
      float z = ziv - f[j2];
      float az = AL_F*z;
      float qq = qi*f[32+j2];
      if constexpr (!P2) {
        float e = 1.0f - fast_erfcf(az);
        S2p += (double)(qq*(z*e + __expf(-az*az)*IAS_F));
        acc += (double)(qq*e);
      } else {
        float dz = vzi - f[64+j2];
        acc += (double)(qq*(K1_F*__expf(-az*az))*dz);
      }
    }
    atomicAdd(&g[tid*3+2], (-8.0*KE_C*PI_D/cell_area(cell))*acc);
    if constexpr (!P2) {
      #pragma unroll
      for (int m=1;m<64;m<<=1) S2p += __shfl_xor(S2p, m);
      if ((tid & 63) == 0) atomicAdd(&scal[((jc*4) & (NCPY-1))*8+1], S2p);
    }
  }

  // ================== last-block epilogue (finish1 / finish2) ===============
  __syncthreads();
  __threadfence();             // make this thread's atomics device-visible
  __syncthreads();
  if (tid == 0){
    int old = __hip_atomic_fetch_add(done, 1, __ATOMIC_ACQ_REL,
                                     __HIP_MEMORY_SCOPE_AGENT);
    amLast = (old == NBLK - 1) ? 1 : 0;
  }
  __syncthreads();
  if (!amLast) return;
  __threadfence();

  int i = tid;
  double s0=0, s1=0, s2v=0;
  for (int c=0;c<NCPY;++c){
    const double* gg = gbase + c*768;
    s0 += gg[i*3+0]; s1 += gg[i*3+1]; s2v += gg[i*3+2];
  }
  shd[i*3+0]=s0; shd[i*3+1]=s1; shd[i*3+2]=s2v;
  __syncthreads();
  if constexpr (!P2) {
    double* ffsh = shd + 768;
    if (i < 12) {
      int mm = i/3, c = i%3;
      double s = 0.0;
      for (int a = 0; a < N_ATOMS; ++a)
        if (im[a] == mm && film[a] > 0) s -= shd[a*3+c];
      ffsh[i] = s;
    }
    __syncthreads();
    {
      double mask = film[i] > 0 ? 1.0 : 0.0;
      int m = im[i];
      V[i*3+0] = mask*ffsh[m*3+0];
      V[i*3+1] = mask*ffsh[m*3+1];
      V[i*3+2] = mask*ffsh[m*3+2];
    }
    if (i == 0) {
      double qs = 0.0;
      for (int a = 0; a < N_ATOMS; ++a){ double qa=(double)q[a]; qs += qa*qa; }
      double area = cell_area(cell);
      double S=0,S2=0,RR=0,bm[4]={0,0,0,0};
      for (int c=0;c<NCPY;++c){
        S += scal[c*8+0]; S2 += scal[c*8+1]; RR += scal[c*8+2];
        for (int m=0;m<4;++m) bm[m] += scal[c*8+3+m];
      }
      double recip = KE_C*PI_D*(S/(2.0*area) - S2/area);
      double realE = 0.5*KE_C*RR;
      double selfE = -ALPHA_C/sqrt(PI_D)*qs*KE_C;
      double Ec = recip + realE + selfE;
      out[4] = (float)Ec;
      for (int m = 0; m < 4; ++m) {
        out[5+m] = (float)bm[m];
        out[m]   = (float)(Ec + bm[m]);
      }
    }
    if (i < 4) {
      double* ff = shd + 768;
      double f0 = ff[i*3+0], f1 = ff[i*3+1], f2 = ff[i*3+2];
      out[9+i] = (float)(f0*f0 + f1*f1 + f2*f2);
    }
  } else {
    if (i < 12) {
      int mm = i/3, c = i%3;
      double s = 0.0;
      for (int a = 0; a < N_ATOMS; ++a)
        if (im[a] == mm && film[a] > 0) s += shd[a*3+c];
      out[13+i] = (float)(-2.0*s);
    }
  }
}

extern "C" void kernel_launch(void* const* d_in, const int* in_sizes, int n_in,
                              void* d_out, int out_size, void* d_ws, size_t ws_size,
                              hipStream_t stream){
  const float* R      = (const float*)d_in[0];
  const float* shiftv = (const float*)d_in[1];
  const float* q      = (const float*)d_in[2];
  const float* offs   = (const float*)d_in[3];
  const float* cell   = (const float*)d_in[4];
  const float* recipc = (const float*)d_in[5];
  const float* r0a    = (const float*)d_in[6];
  const float* na     = (const float*)d_in[7];
  const int*   ii     = (const int*)d_in[8];
  const int*   jj     = (const int*)d_in[9];
  const int*   im     = (const int*)d_in[10];
  const int*   film   = (const int*)d_in[11];
  float* out = (float*)d_out;

  double* ws   = (double*)d_ws;
  double* scal = ws;                    // NCPY x 8 = 256
  double* g32  = ws + 256;              // NCPY x 768
  double* w32  = ws + 256 + NCPY*768;   // NCPY x 768
  double* V    = ws + 256 + 2*NCPY*768; // 768
  int*    done = (int*)(ws + 256 + 2*NCPY*768 + 768);  // 2 counters

  size_t zero_bytes = (size_t)(256 + 2*NCPY*768 + 768)*sizeof(double) + 16;
  hipMemsetAsync((void*)ws, 0, zero_bytes, stream);
  hipLaunchKernelGGL((pass_kernel<0>), dim3(NBLK), dim3(256), 0, stream,
                     R, shiftv, q, offs, cell, recipc, r0a, na, ii, jj, im, film,
                     V, g32, scal, done+0, out);
  hipLaunchKernelGGL((pass_kernel<1>), dim3(NBLK), dim3(256), 0, stream,
                     R, shiftv, q, offs, cell, recipc, r0a, na, ii, jj, im, film,
                     V, w32, scal, done+1, out);
}

// Round 9
// 185.097 us; speedup vs baseline: 2.3834x; 2.3834x over previous
//
#include <hip/hip_runtime.h>
#include <type_traits>

#define N_ATOMS 256
#define N_MOL 4
#define N_PAIRS 8192
#define KE_C 14.3996
#define ALPHA_C 0.3
#define CUTOFF_C 6.0

#define KS_B 1344   // 84 k-pairs x 16 i-chunks
#define RE_B 400    // 25 cells x 16 i-chunks
#define BO_B 32     // 8192 pairs / 256
#define S2_B 8      // 8 j-chunks of 32
#define NBLK (KS_B+RE_B+BO_B+S2_B)
#define NCPY 32

constexpr double PI_D    = 3.14159265358979323846;
constexpr double TWOSQPI = 1.12837916709551257390; // 2/sqrt(pi)
#define AL_F 0.3f
#define TWOSQPI_F 1.12837917f
#define K1_F 0.33851375f    // TWOSQPI*ALPHA
#define IAS_F 1.8806320f    // 1/(ALPHA*sqrt(pi))

// ---------------- fast fp32 erfc (rel err ~1e-6 with __expf) ----------------
__device__ __forceinline__ float fast_erfcf(float x){
  float ax = fabsf(x);
  float t = __fdividef(1.0f, fmaf(0.5f, ax, 1.0f));
  float p = 0.17087277f;
  p = fmaf(p, t, -0.82215223f);
  p = fmaf(p, t,  1.48851587f);
  p = fmaf(p, t, -1.13520398f);
  p = fmaf(p, t,  0.27886807f);
  p = fmaf(p, t, -0.18628806f);
  p = fmaf(p, t,  0.09678418f);
  p = fmaf(p, t,  0.37409196f);
  p = fmaf(p, t,  1.00002368f);
  p = fmaf(p, t, -1.26551223f);
  float ans = t*__expf(fmaf(-ax, ax, p));
  return x >= 0.0f ? ans : 2.0f - ans;
}

// ---------------- dual numbers (fp64, Born HVP) -----------------------------
struct Dd {
  double v, t;
  __device__ Dd() {}
  __device__ Dd(double v_) : v(v_), t(0.0) {}
  __device__ Dd(double v_, double t_) : v(v_), t(t_) {}
};
__device__ inline Dd operator+(Dd a, Dd b){ return Dd(a.v+b.v, a.t+b.t); }
__device__ inline Dd operator+(Dd a, double b){ return Dd(a.v+b, a.t); }
__device__ inline Dd operator-(Dd a, Dd b){ return Dd(a.v-b.v, a.t-b.t); }
__device__ inline Dd operator*(Dd a, Dd b){ return Dd(a.v*b.v, a.t*b.v + a.v*b.t); }
__device__ inline Dd operator*(double a, Dd b){ return Dd(a*b.v, a*b.t); }
__device__ inline double fsqrt(double a){ return sqrt(a); }
__device__ inline Dd     fsqrt(Dd a){ double s=sqrt(a.v); return Dd(s, a.t*0.5/s); }
__device__ inline double finv(double a){ return 1.0/a; }
__device__ inline Dd     finv(Dd a){ double iv=1.0/a.v; return Dd(iv, -a.t*iv*iv); }
__device__ inline double ipown(double x, int e){
  double r = 1.0;
  while (e){ if (e & 1) r *= x; x *= x; e >>= 1; }
  return r;
}
__device__ inline double fpowni(double a, int n){ return ipown(1.0/a, n); }
__device__ inline Dd     fpowni(Dd a, int n){
  double iv = 1.0/a.v; double p = ipown(iv, n);
  return Dd(p, -(double)n*p*iv*a.t);
}
__device__ inline double gval(double a){ return a; }
__device__ inline double gval(Dd a){ return a.v; }
__device__ inline double pick(double a){ return a; }
__device__ inline double pick(Dd a){ return a.t; }
template<class T> __device__ inline T mk(double v, double t){
  if constexpr (std::is_same<T,double>::value) return v; else return Dd(v, t);
}

__device__ inline double cell_area(const float* cell){
  double a0=cell[0], a1=cell[1], a2=cell[2];
  double b0=cell[3], b1=cell[4], b2=cell[5];
  double cx=a1*b2-a2*b1, cy=a2*b0-a0*b2, cz=a0*b1-a1*b0;
  return sqrt(cx*cx+cy*cy+cz*cz);
}
// Rs[a][c] = R + film*shift[mol]
__device__ inline double posc(const float* R, const float* shiftv, const int* im,
                              const int* film, int a, int c){
  double mask = film[a] > 0 ? 1.0 : 0.0;
  return (double)R[a*3+c] + mask*(double)shiftv[im[a]*3+c];
}

// ---------------- pass kernel (P2=0: grad+energies; P2=1: HVP) --------------
template<int P2>
__global__ __launch_bounds__(256) void pass_kernel(
    const float* R, const float* shiftv, const float* q, const float* offs,
    const float* cell, const float* recipc, const float* r0a, const float* na,
    const int* ii, const int* jj, const int* im, const int* film,
    const double* Vt, double* gbase, double* scal){
  __shared__ float f[2048];     // 8 KB staging
  __shared__ double red[16];
  int b = blockIdx.x, tid = threadIdx.x;

  if (b < KS_B) {
    // ================= k-space: kk = b>>4, i-chunk ic = b&15 ================
    int kk = b >> 4, ic = b & 15;
    int cp = (kk + 2*ic) & (NCPY-1);
    double* g = gbase + cp*768;
    double b0 = (double)(kk/13 - 6), b1d = (double)(kk%13 - 6);
    double TP = 2.0*PI_D;
    double h0d = TP*(b0*(double)recipc[0] + b1d*(double)recipc[3]);
    double h1d = TP*(b0*(double)recipc[1] + b1d*(double)recipc[4]);
    double h2d = TP*(b0*(double)recipc[2] + b1d*(double)recipc[5]);
    double kapd = sqrt(h0d*h0d + h1d*h1d + h2d*h2d);
    float A    = (float)(kapd/(2.0*ALPHA_C));
    float ikap = (float)(1.0/kapd);
    float kapf = (float)kapd;
    {   // stage all 256 atoms' per-k entries (each thread computes one atom)
      int a = tid;
      double xa = posc(R,shiftv,im,film,a,0);
      double ya = posc(R,shiftv,im,film,a,1);
      double za = posc(R,shiftv,im,film,a,2);
      double phi = h0d*xa + h1d*ya + h2d*za;
      double s, c; sincos(phi, &s, &c);
      double E = exp(kapd*za);
      f[a]      = (float)c;       f[256+a]  = (float)s;
      f[512+a]  = (float)E;       f[768+a]  = (float)(1.0/E);
      f[1024+a] = (float)za;      f[1280+a] = q[a];
      if constexpr (P2) {
        f[1536+a] = (float)(h0d*Vt[a*3+0] + h1d*Vt[a*3+1] + h2d*Vt[a*3+2]);
        f[1792+a] = (float)Vt[a*3+2];
      }
    }
    __syncthreads();
    int il = tid >> 4, jl = tid & 15;
    int i = ic*16 + il;
    float ci=f[i], si=f[256+i], Ei=f[512+i], iEi=f[768+i];
    float zi=f[1024+i], qi=f[1280+i];
    float dpi=0.f, vzi=0.f;
    if constexpr (P2) { dpi = f[1536+i]; vzi = f[1792+i]; }
    double Sp=0.0, cmS=0.0, czS=0.0;
    #pragma unroll 4
    for (int t=0;t<16;++t){
      int j = t*16 + jl;
      float z  = zi - f[1024+j];
      float az = AL_F*z;
      float u1 = A + az, u2 = A - az;
      float ec1 = fast_erfcf(u1), ec2 = fast_erfcf(u2);
      float ekz = Ei*f[768+j], ikz = iEi*f[512+j];
      float e1 = ekz*ec1, e2 = ikz*ec2;
      float cj = f[j], sj = f[256+j];
      float cph = ci*cj + si*sj;
      float sph = si*cj - ci*sj;
      float fF  = (e1+e2)*ikap;
      float qq  = qi*f[1280+j];
      if constexpr (!P2) {
        Sp  += (double)(qq*cph*fF);
        cmS += (double)(-2.0f*qq*sph*fF);
        czS += (double)( 2.0f*qq*cph*(e1-e2));
      } else {
        float dz   = vzi - f[1792+j];
        float dphi = dpi - f[1536+j];
        float g1 = TWOSQPI_F*__expf(-u1*u1);
        float g2 = TWOSQPI_F*__expf(-u2*u2);
        float de1 = dz*(kapf*e1 - AL_F*ekz*g1);
        float de2 = dz*(AL_F*ikz*g2 - kapf*e2);
        float dF  = (de1+de2)*ikap;
        float dcs = -sph*dphi, dsn = cph*dphi;
        cmS += (double)(-2.0f*qq*(dsn*fF + sph*dF));
        czS += (double)( 2.0f*qq*(dcs*(e1-e2) + cph*(de1-de2)));
      }
    }
    // reduce over the 16 j-lanes (lanes differ only in bits 0..3)
    #pragma unroll
    for (int m=1;m<16;m<<=1){
      cmS += __shfl_xor(cmS, m);
      czS += __shfl_xor(czS, m);
      if constexpr (!P2) Sp += __shfl_xor(Sp, m);
    }
    if (jl == 0){
      double gsc = 4.0*KE_C*PI_D/cell_area(cell);   // x4 mol, x2 +-k fold
      atomicAdd(&g[i*3+0], gsc*(h0d*cmS));
      atomicAdd(&g[i*3+1], gsc*(h1d*cmS));
      atomicAdd(&g[i*3+2], gsc*(h2d*cmS + czS));
      if constexpr (!P2) red[il] = Sp;
    }
    if constexpr (!P2){
      __syncthreads();
      if (tid == 0){
        double s = 0.0;
        #pragma unroll
        for (int u=0;u<16;++u) s += red[u];
        atomicAdd(&scal[cp*8+0], 2.0*s);
      }
    }
  } else if (b < KS_B + RE_B) {
    // ================= real space: nn = r>>4, i-chunk = r&15 ================
    int r = b - KS_B; int nn = r >> 4, ic = r & 15;
    int cp = (nn + 2*ic) & (NCPY-1);
    double* g = gbase + cp*768;
    double n0 = (double)(nn/5 - 2), n1 = (double)(nn%5 - 2);
    float a0 = (float)(n0*(double)cell[0] + n1*(double)cell[3]);
    float a1 = (float)(n0*(double)cell[1] + n1*(double)cell[4]);
    float a2 = (float)(n0*(double)cell[2] + n1*(double)cell[5]);
    {
      int a = tid;
      f[a]      = (float)posc(R,shiftv,im,film,a,0);
      f[256+a]  = (float)posc(R,shiftv,im,film,a,1);
      f[512+a]  = (float)posc(R,shiftv,im,film,a,2);
      f[768+a]  = q[a];
      if constexpr (P2) {
        f[1024+a]=(float)Vt[a*3+0]; f[1280+a]=(float)Vt[a*3+1]; f[1536+a]=(float)Vt[a*3+2];
      }
    }
    __syncthreads();
    int il = tid >> 4, jl = tid & 15;
    int i = ic*16 + il;
    float xi=f[i], yi=f[256+i], zi=f[512+i], qi=f[768+i];
    float vxi=0.f, vyi=0.f, vzi=0.f;
    if constexpr (P2){ vxi=f[1024+i]; vyi=f[1280+i]; vzi=f[1536+i]; }
    double gx=0,gy=0,gz=0,Rp=0;
    #pragma unroll 4
    for (int t=0;t<16;++t){
      int j = t*16 + jl;
      float rx = xi - f[j]     + a0;
      float ry = yi - f[256+j] + a1;
      float rz = zi - f[512+j] + a2;
      float dsq = rx*rx+ry*ry+rz*rz;
      if (dsq > 0.0f){
        float d = sqrtf(dsq);
        float invd = __fdividef(1.0f, d);
        float ad = AL_F*d;
        float ec = fast_erfcf(ad);
        float ex = __expf(-ad*ad);
        float qq = qi*f[768+j];
        float P  = -(K1_F*ex*invd + ec*invd*invd);
        float C  = qq*P*invd;
        if constexpr (!P2) {
          Rp += (double)(qq*ec*invd);
          gx += (double)(C*rx); gy += (double)(C*ry); gz += (double)(C*rz);
        } else {
          float drx = vxi - f[1024+j], dry = vyi - f[1280+j], drz = vzi - f[1536+j];
          float dd  = (rx*drx + ry*dry + rz*drz)*invd;
          float invd2 = invd*invd;
          float dC = qq*dd*( K1_F*ex*(2.0f*AL_F*AL_F + 3.0f*invd2)*invd
                             + 3.0f*ec*invd2*invd2 );
          gx += (double)(dC*rx + C*drx);
          gy += (double)(dC*ry + C*dry);
          gz += (double)(dC*rz + C*drz);
        }
      }
    }
    #pragma unroll
    for (int m=1;m<16;m<<=1){
      gx += __shfl_xor(gx, m); gy += __shfl_xor(gy, m); gz += __shfl_xor(gz, m);
      if constexpr (!P2) Rp += __shfl_xor(Rp, m);
    }
    if (jl == 0){
      atomicAdd(&g[i*3+0], 4.0*KE_C*gx);
      atomicAdd(&g[i*3+1], 4.0*KE_C*gy);
      atomicAdd(&g[i*3+2], 4.0*KE_C*gz);
      if constexpr (!P2) red[il] = Rp;
    }
    if constexpr (!P2){
      __syncthreads();
      if (tid == 0){
        double s = 0.0;
        #pragma unroll
        for (int u=0;u<16;++u) s += red[u];
        atomicAdd(&scal[cp*8+2], s);
      }
    }
  } else if (b < KS_B + RE_B + BO_B) {
    // ================= Born (fp64 / dual), integer pow ======================
    using T = typename std::conditional<P2, Dd, double>::type;
    int bb = b - KS_B - RE_B;
    int cp = bb & (NCPY-1);
    double* g = gbase + cp*768;
    int p = bb*256 + tid;
    int ai = ii[p], aj = jj[p];
    double pix = posc(R,shiftv,im,film,ai,0), pjx = posc(R,shiftv,im,film,aj,0);
    double piy = posc(R,shiftv,im,film,ai,1), pjy = posc(R,shiftv,im,film,aj,1);
    double piz = posc(R,shiftv,im,film,ai,2), pjz = posc(R,shiftv,im,film,aj,2);
    double tx=0.0, ty=0.0, tz=0.0;
    if constexpr (P2){
      tx = Vt[aj*3+0]-Vt[ai*3+0];
      ty = Vt[aj*3+1]-Vt[ai*3+1];
      tz = Vt[aj*3+2]-Vt[ai*3+2];
    }
    T rx = mk<T>(pjx-pix+(double)offs[p*3+0], tx);
    T ry = mk<T>(pjy-piy+(double)offs[p*3+1], ty);
    T rz = mk<T>(pjz-piz+(double)offs[p*3+2], tz);
    T dsq = rx*rx + ry*ry + rz*rz;
    T d = fsqrt(dsq);
    double y = 0.0;
    if (gval(d) < CUTOFF_C) {
      double qq = fabs((double)q[ai]*(double)q[aj]);
      int    ni = (int)(na[p] + 0.5f);
      double n  = (double)ni;
      double B  = qq * ipown((double)r0a[p], ni-1) / n;
      T dmn = fpowni(d, ni);
      if constexpr (!P2)
        y = 0.5*KE_C*B*(gval(dmn) - ipown(1.0/CUTOFF_C, ni));
      T c = (-0.5*KE_C*n*B) * (dmn * finv(dsq));
      T fx = c*rx, fy = c*ry, fz = c*rz;
      atomicAdd(&g[aj*3+0],  pick(fx));
      atomicAdd(&g[aj*3+1],  pick(fy));
      atomicAdd(&g[aj*3+2],  pick(fz));
      atomicAdd(&g[ai*3+0], -pick(fx));
      atomicAdd(&g[ai*3+1], -pick(fy));
      atomicAdd(&g[ai*3+2], -pick(fz));
    }
    if constexpr (!P2) {
      int myMol = im[ai];
      #pragma unroll
      for (int mm=0; mm<4; ++mm){
        double v = (myMol==mm) ? y : 0.0;
        for (int off=32; off; off>>=1) v += __shfl_down(v, off, 64);
        if ((tid & 63) == 0 && v != 0.0)
          atomicAdd(&scal[cp*8+3+mm], v);
      }
    }
  } else {
    // ================= S2 (fp32): i = tid, 32-j chunk =======================
    int jc = b - (KS_B + RE_B + BO_B);
    int cp = (jc*4) & (NCPY-1);
    double* g = gbase + cp*768;
    if (tid < 32) {
      int j = jc*32 + tid;
      f[tid]    = (float)posc(R,shiftv,im,film,j,2);
      f[32+tid] = q[j];
      f[64+tid] = P2 ? (float)Vt[j*3+2] : 0.0f;
    }
    __syncthreads();
    float ziv = (float)posc(R,shiftv,im,film,tid,2), qi = q[tid];
    float vzi = 0.0f;
    if constexpr (P2) vzi = (float)Vt[tid*3+2];
    double acc = 0.0, S2p = 0.0;
    for (int j2=0;j2<32;++j2){
      float z = ziv - f[j2];
      float az = AL_F*z;
      float qq = qi*f[32+j2];
      if constexpr (!P2) {
        float e = 1.0f - fast_erfcf(az);
        S2p += (double)(qq*(z*e + __expf(-az*az)*IAS_F));
        acc += (double)(qq*e);
      } else {
        float dz = vzi - f[64+j2];
        acc += (double)(qq*(K1_F*__expf(-az*az))*dz);
      }
    }
    atomicAdd(&g[tid*3+2], (-8.0*KE_C*PI_D/cell_area(cell))*acc);
    if constexpr (!P2) {
      #pragma unroll
      for (int m=1;m<64;m<<=1) S2p += __shfl_xor(S2p, m);
      if ((tid & 63) == 0) atomicAdd(&scal[cp*8+1], S2p);
    }
  }
}

// ---------------- finish1: energies, ffn, V ---------------------------------
__global__ void finish1_kernel(const double* gN, const double* scal, const float* q,
                               const float* cell, const int* im, const int* film,
                               double* V, float* out){
  int i = threadIdx.x;
  __shared__ double gsh[256*3];
  __shared__ double ffsh[12];
  double s0=0,s1=0,s2v=0;
  for (int c=0;c<NCPY;++c){
    const double* g = gN + c*768;
    s0 += g[i*3+0]; s1 += g[i*3+1]; s2v += g[i*3+2];
  }
  gsh[i*3+0]=s0; gsh[i*3+1]=s1; gsh[i*3+2]=s2v;
  __syncthreads();
  if (i < 12) {
    int mm = i/3, c = i%3;
    double s = 0.0;
    for (int a = 0; a < N_ATOMS; ++a)
      if (im[a] == mm && film[a] > 0) s -= gsh[a*3+c];
    ffsh[i] = s;
  }
  __syncthreads();
  {
    double mask = film[i] > 0 ? 1.0 : 0.0;
    int m = im[i];
    V[i*3+0] = mask*ffsh[m*3+0];
    V[i*3+1] = mask*ffsh[m*3+1];
    V[i*3+2] = mask*ffsh[m*3+2];
  }
  if (i == 0) {
    double qs = 0.0;
    for (int a = 0; a < N_ATOMS; ++a){ double qa=(double)q[a]; qs += qa*qa; }
    double area = cell_area(cell);
    double S=0,S2=0,RR=0,bm[4]={0,0,0,0};
    for (int c=0;c<NCPY;++c){
      S += scal[c*8+0]; S2 += scal[c*8+1]; RR += scal[c*8+2];
      for (int m=0;m<4;++m) bm[m] += scal[c*8+3+m];
    }
    double recip = KE_C*PI_D*(S/(2.0*area) - S2/area);
    double realE = 0.5*KE_C*RR;
    double selfE = -ALPHA_C/sqrt(PI_D)*qs*KE_C;
    double Ec = recip + realE + selfE;
    out[4] = (float)Ec;
    for (int m = 0; m < 4; ++m) {
      out[5+m] = (float)bm[m];
      out[m]   = (float)(Ec + bm[m]);
    }
  }
  if (i < 4) {
    double f0 = ffsh[i*3+0], f1 = ffsh[i*3+1], f2 = ffsh[i*3+2];
    out[9+i] = (float)(f0*f0 + f1*f1 + f2*f2);
  }
}

// ---------------- finish2: fng = -2 * segsum(mask * Hv) ---------------------
__global__ void finish2_kernel(const double* wN, const int* im, const int* film,
                               float* out){
  int i = threadIdx.x;
  __shared__ double gsh[256*3];
  double s0=0,s1=0,s2v=0;
  for (int c=0;c<NCPY;++c){
    const double* w = wN + c*768;
    s0 += w[i*3+0]; s1 += w[i*3+1]; s2v += w[i*3+2];
  }
  gsh[i*3+0]=s0; gsh[i*3+1]=s1; gsh[i*3+2]=s2v;
  __syncthreads();
  if (i < 12) {
    int mm = i/3, c = i%3;
    double s = 0.0;
    for (int a = 0; a < N_ATOMS; ++a)
      if (im[a] == mm && film[a] > 0) s += gsh[a*3+c];
    out[13+i] = (float)(-2.0*s);
  }
}

extern "C" void kernel_launch(void* const* d_in, const int* in_sizes, int n_in,
                              void* d_out, int out_size, void* d_ws, size_t ws_size,
                              hipStream_t stream){
  const float* R      = (const float*)d_in[0];
  const float* shiftv = (const float*)d_in[1];
  const float* q      = (const float*)d_in[2];
  const float* offs   = (const float*)d_in[3];
  const float* cell   = (const float*)d_in[4];
  const float* recipc = (const float*)d_in[5];
  const float* r0a    = (const float*)d_in[6];
  const float* na     = (const float*)d_in[7];
  const int*   ii     = (const int*)d_in[8];
  const int*   jj     = (const int*)d_in[9];
  const int*   im     = (const int*)d_in[10];
  const int*   film   = (const int*)d_in[11];
  float* out = (float*)d_out;

  double* ws   = (double*)d_ws;
  double* scal = ws;                    // NCPY x 8 = 256
  double* gN   = ws + 256;              // NCPY x 768
  double* wN   = ws + 256 + NCPY*768;   // NCPY x 768
  double* V    = ws + 256 + 2*NCPY*768; // 768 (written fully by finish1)

  size_t zero_words = (size_t)(256 + 2*NCPY*768 + 768);
  hipMemsetAsync((void*)ws, 0, zero_words*sizeof(double), stream);
  hipLaunchKernelGGL((pass_kernel<0>), dim3(NBLK), dim3(256), 0, stream,
                     R, shiftv, q, offs, cell, recipc, r0a, na, ii, jj, im, film,
                     V, gN, scal);
  hipLaunchKernelGGL(finish1_kernel, dim3(1), dim3(256), 0, stream,
                     gN, scal, q, cell, im, film, V, out);
  hipLaunchKernelGGL((pass_kernel<1>), dim3(NBLK), dim3(256), 0, stream,
                     R, shiftv, q, offs, cell, recipc, r0a, na, ii, jj, im, film,
                     V, wN, scal);
  hipLaunchKernelGGL(finish2_kernel, dim3(1), dim3(256), 0, stream,
                     wN, im, film, out);
}

// Round 10
// 182.408 us; speedup vs baseline: 2.4186x; 1.0147x over previous
//
#include <hip/hip_runtime.h>
#include <type_traits>

#define N_ATOMS 256
#define N_MOL 4
#define N_PAIRS 8192
#define KE_C 14.3996
#define ALPHA_C 0.3
#define CUTOFF_C 6.0

#define KS_B 1344   // 84 k-pairs x 16 i-chunks
#define RE_B 400    // 25 cells x 16 i-chunks
#define BO_B 32     // 8192 pairs / 256
#define S2_B 8      // 8 j-chunks of 32
#define NBLK (KS_B+RE_B+BO_B+S2_B)
#define NCPY 32
#define NPREP 85
#define ZWORDS (256 + 2*NCPY*768 + 768)   // scal + gN + wN + V = 50176 doubles

constexpr double PI_D    = 3.14159265358979323846;
constexpr double TWOSQPI = 1.12837916709551257390; // 2/sqrt(pi)
#define AL_F 0.3f
#define TWOSQPI_F 1.12837917f
#define K1_F 0.33851375f    // TWOSQPI*ALPHA
#define IAS_F 1.8806320f    // 1/(ALPHA*sqrt(pi))

// ---------------- fast fp32 erfc (rel err ~1e-6 with __expf) ----------------
__device__ __forceinline__ float fast_erfcf(float x){
  float ax = fabsf(x);
  float t = __fdividef(1.0f, fmaf(0.5f, ax, 1.0f));
  float p = 0.17087277f;
  p = fmaf(p, t, -0.82215223f);
  p = fmaf(p, t,  1.48851587f);
  p = fmaf(p, t, -1.13520398f);
  p = fmaf(p, t,  0.27886807f);
  p = fmaf(p, t, -0.18628806f);
  p = fmaf(p, t,  0.09678418f);
  p = fmaf(p, t,  0.37409196f);
  p = fmaf(p, t,  1.00002368f);
  p = fmaf(p, t, -1.26551223f);
  float ans = t*__expf(fmaf(-ax, ax, p));
  return x >= 0.0f ? ans : 2.0f - ans;
}

// ---------------- dual numbers (fp64, Born HVP) -----------------------------
struct Dd {
  double v, t;
  __device__ Dd() {}
  __device__ Dd(double v_) : v(v_), t(0.0) {}
  __device__ Dd(double v_, double t_) : v(v_), t(t_) {}
};
__device__ inline Dd operator+(Dd a, Dd b){ return Dd(a.v+b.v, a.t+b.t); }
__device__ inline Dd operator+(Dd a, double b){ return Dd(a.v+b, a.t); }
__device__ inline Dd operator-(Dd a, Dd b){ return Dd(a.v-b.v, a.t-b.t); }
__device__ inline Dd operator*(Dd a, Dd b){ return Dd(a.v*b.v, a.t*b.v + a.v*b.t); }
__device__ inline Dd operator*(double a, Dd b){ return Dd(a*b.v, a*b.t); }
__device__ inline double fsqrt(double a){ return sqrt(a); }
__device__ inline Dd     fsqrt(Dd a){ double s=sqrt(a.v); return Dd(s, a.t*0.5/s); }
__device__ inline double finv(double a){ return 1.0/a; }
__device__ inline Dd     finv(Dd a){ double iv=1.0/a.v; return Dd(iv, -a.t*iv*iv); }
__device__ inline double ipown(double x, int e){
  double r = 1.0;
  while (e){ if (e & 1) r *= x; x *= x; e >>= 1; }
  return r;
}
__device__ inline double fpowni(double a, int n){ return ipown(1.0/a, n); }
__device__ inline Dd     fpowni(Dd a, int n){
  double iv = 1.0/a.v; double p = ipown(iv, n);
  return Dd(p, -(double)n*p*iv*a.t);
}
__device__ inline double gval(double a){ return a; }
__device__ inline double gval(Dd a){ return a.v; }
__device__ inline double pick(double a){ return a; }
__device__ inline double pick(Dd a){ return a.t; }
template<class T> __device__ inline T mk(double v, double t){
  if constexpr (std::is_same<T,double>::value) return v; else return Dd(v, t);
}

__device__ inline double cell_area(const float* cell){
  double a0=cell[0], a1=cell[1], a2=cell[2];
  double b0=cell[3], b1=cell[4], b2=cell[5];
  double cx=a1*b2-a2*b1, cy=a2*b0-a0*b2, cz=a0*b1-a1*b0;
  return sqrt(cx*cx+cy*cy+cz*cz);
}
// Rs[a][c] = R + film*shift[mol]
__device__ inline double posc(const float* R, const float* shiftv, const int* im,
                              const int* film, int a, int c){
  double mask = film[a] > 0 ? 1.0 : 0.0;
  return (double)R[a*3+c] + mask*(double)shiftv[im[a]*3+c];
}

// ---------------- prep: zero accumulators; build k-table + pos table --------
__global__ __launch_bounds__(256) void prep_kernel(
    const float* R, const float* shiftv, const float* q, const int* im,
    const int* film, const float* recipc, double* ws, float4* tab4, float4* posf4){
  int b = blockIdx.x, tid = threadIdx.x;
  for (int w = b*256 + tid; w < ZWORDS; w += NPREP*256) ws[w] = 0.0;
  int a = tid;
  double xa = posc(R,shiftv,im,film,a,0);
  double ya = posc(R,shiftv,im,film,a,1);
  double za = posc(R,shiftv,im,film,a,2);
  if (b < 84) {
    double b0 = (double)(b/13 - 6), b1 = (double)(b%13 - 6);
    double TP = 2.0*PI_D;
    double h0 = TP*(b0*(double)recipc[0] + b1*(double)recipc[3]);
    double h1 = TP*(b0*(double)recipc[1] + b1*(double)recipc[4]);
    double h2 = TP*(b0*(double)recipc[2] + b1*(double)recipc[5]);
    double kap = sqrt(h0*h0 + h1*h1 + h2*h2);
    double phi = h0*xa + h1*ya + h2*za;
    double s, c; sincos(phi, &s, &c);
    double E = exp(kap*za);
    tab4[b*256+a] = make_float4((float)c, (float)s, (float)E, (float)(1.0/E));
  } else if (b == 84) {
    posf4[a] = make_float4((float)xa, (float)ya, (float)za, q[a]);
  }
}

// ---------------- pass kernel (P2=0: grad+energies; P2=1: HVP) --------------
template<int P2>
__global__ __launch_bounds__(256) void pass_kernel(
    const float* R, const float* shiftv, const float* q, const float* offs,
    const float* cell, const float* recipc, const float* r0a, const float* na,
    const int* ii, const int* jj, const int* im, const int* film,
    const double* Vt, const float4* tab4, const float4* posf4,
    double* gbase, double* scal){
  __shared__ __align__(16) float fbuf[2048];   // 8 KB aliased staging
  __shared__ double red[16];
  int b = blockIdx.x, tid = threadIdx.x;

  if (b < KS_B) {
    // ================= k-space: kk = b>>4, i-chunk ic = b&15 ================
    int kk = b >> 4, ic = b & 15;
    int cp = (kk + 2*ic) & (NCPY-1);
    double* g = gbase + cp*768;
    double b0 = (double)(kk/13 - 6), b1d = (double)(kk%13 - 6);
    double TP = 2.0*PI_D;
    double h0d = TP*(b0*(double)recipc[0] + b1d*(double)recipc[3]);
    double h1d = TP*(b0*(double)recipc[1] + b1d*(double)recipc[4]);
    double h2d = TP*(b0*(double)recipc[2] + b1d*(double)recipc[5]);
    double kapd = sqrt(h0d*h0d + h1d*h1d + h2d*h2d);
    float A    = (float)(kapd/(2.0*ALPHA_C));
    float ikap = (float)(1.0/kapd);
    float kapf = (float)kapd;
    float4* t4 = (float4*)fbuf;        // [0,1024) floats
    float*  pzs = fbuf + 1024;
    float*  pqs = fbuf + 1280;
    float*  dps = fbuf + 1536;
    float*  vzs = fbuf + 1792;
    {   // stage from precomputed tables (coalesced float4 loads, no fp64 math)
      int a = tid;
      t4[a] = tab4[kk*256 + a];
      float4 p = posf4[a];
      pzs[a] = p.z; pqs[a] = p.w;
      if constexpr (P2) {
        dps[a] = (float)(h0d*Vt[a*3+0] + h1d*Vt[a*3+1] + h2d*Vt[a*3+2]);
        vzs[a] = (float)Vt[a*3+2];
      }
    }
    __syncthreads();
    int il = tid >> 4, jl = tid & 15;
    int i = ic*16 + il;
    float4 ti = t4[i];
    float ci=ti.x, si=ti.y, Ei=ti.z, iEi=ti.w;
    float zi=pzs[i], qi=pqs[i];
    float dpi=0.f, vzi=0.f;
    if constexpr (P2) { dpi = dps[i]; vzi = vzs[i]; }
    double Sp=0.0, cmS=0.0, czS=0.0;
    #pragma unroll 4
    for (int t=0;t<16;++t){
      int j = t*16 + jl;
      float4 tj = t4[j];
      float z  = zi - pzs[j];
      float az = AL_F*z;
      float u1 = A + az, u2 = A - az;
      float ec1 = fast_erfcf(u1), ec2 = fast_erfcf(u2);
      float ekz = Ei*tj.w, ikz = iEi*tj.z;
      float e1 = ekz*ec1, e2 = ikz*ec2;
      float cph = ci*tj.x + si*tj.y;
      float sph = si*tj.x - ci*tj.y;
      float fF  = (e1+e2)*ikap;
      float qq  = qi*pqs[j];
      if constexpr (!P2) {
        Sp  += (double)(qq*cph*fF);
        cmS += (double)(-2.0f*qq*sph*fF);
        czS += (double)( 2.0f*qq*cph*(e1-e2));
      } else {
        float dz   = vzi - vzs[j];
        float dphi = dpi - dps[j];
        float g1 = TWOSQPI_F*__expf(-u1*u1);
        float g2 = TWOSQPI_F*__expf(-u2*u2);
        float de1 = dz*(kapf*e1 - AL_F*ekz*g1);
        float de2 = dz*(AL_F*ikz*g2 - kapf*e2);
        float dF  = (de1+de2)*ikap;
        float dcs = -sph*dphi, dsn = cph*dphi;
        cmS += (double)(-2.0f*qq*(dsn*fF + sph*dF));
        czS += (double)( 2.0f*qq*(dcs*(e1-e2) + cph*(de1-de2)));
      }
    }
    // reduce over the 16 j-lanes (lanes differ only in bits 0..3)
    #pragma unroll
    for (int m=1;m<16;m<<=1){
      cmS += __shfl_xor(cmS, m);
      czS += __shfl_xor(czS, m);
      if constexpr (!P2) Sp += __shfl_xor(Sp, m);
    }
    if (jl == 0){
      double gsc = 4.0*KE_C*PI_D/cell_area(cell);   // x4 mol, x2 +-k fold
      atomicAdd(&g[i*3+0], gsc*(h0d*cmS));
      atomicAdd(&g[i*3+1], gsc*(h1d*cmS));
      atomicAdd(&g[i*3+2], gsc*(h2d*cmS + czS));
      if constexpr (!P2) red[il] = Sp;
    }
    if constexpr (!P2){
      __syncthreads();
      if (tid == 0){
        double s = 0.0;
        #pragma unroll
        for (int u=0;u<16;++u) s += red[u];
        atomicAdd(&scal[cp*8+0], 2.0*s);
      }
    }
  } else if (b < KS_B + RE_B) {
    // ================= real space: nn = r>>4, i-chunk = r&15 ================
    int r = b - KS_B; int nn = r >> 4, ic = r & 15;
    int cp = (nn + 2*ic) & (NCPY-1);
    double* g = gbase + cp*768;
    double n0 = (double)(nn/5 - 2), n1 = (double)(nn%5 - 2);
    float a0 = (float)(n0*(double)cell[0] + n1*(double)cell[3]);
    float a1 = (float)(n0*(double)cell[1] + n1*(double)cell[4]);
    float a2 = (float)(n0*(double)cell[2] + n1*(double)cell[5]);
    float *px=fbuf, *py=fbuf+256, *pz=fbuf+512, *pq=fbuf+768,
          *vx=fbuf+1024, *vy=fbuf+1280, *vz=fbuf+1536;
    {
      int a = tid;
      float4 p = posf4[a];
      px[a]=p.x; py[a]=p.y; pz[a]=p.z; pq[a]=p.w;
      if constexpr (P2) {
        vx[a]=(float)Vt[a*3+0]; vy[a]=(float)Vt[a*3+1]; vz[a]=(float)Vt[a*3+2];
      }
    }
    __syncthreads();
    int il = tid >> 4, jl = tid & 15;
    int i = ic*16 + il;
    float xi=px[i], yi=py[i], zi=pz[i], qi=pq[i];
    float vxi=0.f, vyi=0.f, vzi=0.f;
    if constexpr (P2){ vxi=vx[i]; vyi=vy[i]; vzi=vz[i]; }
    double gx=0,gy=0,gz=0,Rp=0;
    #pragma unroll 4
    for (int t=0;t<16;++t){
      int j = t*16 + jl;
      float rx = xi - px[j] + a0;
      float ry = yi - py[j] + a1;
      float rz = zi - pz[j] + a2;
      float dsq = rx*rx+ry*ry+rz*rz;
      if (dsq > 0.0f){
        float d = sqrtf(dsq);
        float invd = __fdividef(1.0f, d);
        float ad = AL_F*d;
        float ec = fast_erfcf(ad);
        float ex = __expf(-ad*ad);
        float qq = qi*pq[j];
        float P  = -(K1_F*ex*invd + ec*invd*invd);
        float C  = qq*P*invd;
        if constexpr (!P2) {
          Rp += (double)(qq*ec*invd);
          gx += (double)(C*rx); gy += (double)(C*ry); gz += (double)(C*rz);
        } else {
          float drx = vxi - vx[j], dry = vyi - vy[j], drz = vzi - vz[j];
          float dd  = (rx*drx + ry*dry + rz*drz)*invd;
          float invd2 = invd*invd;
          float dC = qq*dd*( K1_F*ex*(2.0f*AL_F*AL_F + 3.0f*invd2)*invd
                             + 3.0f*ec*invd2*invd2 );
          gx += (double)(dC*rx + C*drx);
          gy += (double)(dC*ry + C*dry);
          gz += (double)(dC*rz + C*drz);
        }
      }
    }
    #pragma unroll
    for (int m=1;m<16;m<<=1){
      gx += __shfl_xor(gx, m); gy += __shfl_xor(gy, m); gz += __shfl_xor(gz, m);
      if constexpr (!P2) Rp += __shfl_xor(Rp, m);
    }
    if (jl == 0){
      atomicAdd(&g[i*3+0], 4.0*KE_C*gx);
      atomicAdd(&g[i*3+1], 4.0*KE_C*gy);
      atomicAdd(&g[i*3+2], 4.0*KE_C*gz);
      if constexpr (!P2) red[il] = Rp;
    }
    if constexpr (!P2){
      __syncthreads();
      if (tid == 0){
        double s = 0.0;
        #pragma unroll
        for (int u=0;u<16;++u) s += red[u];
        atomicAdd(&scal[cp*8+2], s);
      }
    }
  } else if (b < KS_B + RE_B + BO_B) {
    // ================= Born (fp64 / dual), integer pow ======================
    using T = typename std::conditional<P2, Dd, double>::type;
    int bb = b - KS_B - RE_B;
    int cp = bb & (NCPY-1);
    double* g = gbase + cp*768;
    int p = bb*256 + tid;
    int ai = ii[p], aj = jj[p];
    double pix = posc(R,shiftv,im,film,ai,0), pjx = posc(R,shiftv,im,film,aj,0);
    double piy = posc(R,shiftv,im,film,ai,1), pjy = posc(R,shiftv,im,film,aj,1);
    double piz = posc(R,shiftv,im,film,ai,2), pjz = posc(R,shiftv,im,film,aj,2);
    double tx=0.0, ty=0.0, tz=0.0;
    if constexpr (P2){
      tx = Vt[aj*3+0]-Vt[ai*3+0];
      ty = Vt[aj*3+1]-Vt[ai*3+1];
      tz = Vt[aj*3+2]-Vt[ai*3+2];
    }
    T rx = mk<T>(pjx-pix+(double)offs[p*3+0], tx);
    T ry = mk<T>(pjy-piy+(double)offs[p*3+1], ty);
    T rz = mk<T>(pjz-piz+(double)offs[p*3+2], tz);
    T dsq = rx*rx + ry*ry + rz*rz;
    T d = fsqrt(dsq);
    double y = 0.0;
    if (gval(d) < CUTOFF_C) {
      double qq = fabs((double)q[ai]*(double)q[aj]);
      int    ni = (int)(na[p] + 0.5f);
      double n  = (double)ni;
      double B  = qq * ipown((double)r0a[p], ni-1) / n;
      T dmn = fpowni(d, ni);
      if constexpr (!P2)
        y = 0.5*KE_C*B*(gval(dmn) - ipown(1.0/CUTOFF_C, ni));
      T c = (-0.5*KE_C*n*B) * (dmn * finv(dsq));
      T fx = c*rx, fy = c*ry, fz = c*rz;
      atomicAdd(&g[aj*3+0],  pick(fx));
      atomicAdd(&g[aj*3+1],  pick(fy));
      atomicAdd(&g[aj*3+2],  pick(fz));
      atomicAdd(&g[ai*3+0], -pick(fx));
      atomicAdd(&g[ai*3+1], -pick(fy));
      atomicAdd(&g[ai*3+2], -pick(fz));
    }
    if constexpr (!P2) {
      int myMol = im[ai];
      #pragma unroll
      for (int mm=0; mm<4; ++mm){
        double v = (myMol==mm) ? y : 0.0;
        for (int off=32; off; off>>=1) v += __shfl_down(v, off, 64);
        if ((tid & 63) == 0 && v != 0.0)
          atomicAdd(&scal[cp*8+3+mm], v);
      }
    }
  } else {
    // ================= S2 (fp32): i = tid, 32-j chunk =======================
    int jc = b - (KS_B + RE_B + BO_B);
    int cp = (jc*4) & (NCPY-1);
    double* g = gbase + cp*768;
    float *zz=fbuf, *zq=fbuf+32, *zv=fbuf+64;
    if (tid < 32) {
      int j = jc*32 + tid;
      float4 p = posf4[j];
      zz[tid] = p.z;
      zq[tid] = p.w;
      zv[tid] = P2 ? (float)Vt[j*3+2] : 0.0f;
    }
    __syncthreads();
    float4 pi = posf4[tid];
    float ziv = pi.z, qi = pi.w;
    float vzi = 0.0f;
    if constexpr (P2) vzi = (float)Vt[tid*3+2];
    double acc = 0.0, S2p = 0.0;
    for (int j2=0;j2<32;++j2){
      float z = ziv - zz[j2];
      float az = AL_F*z;
      float qq = qi*zq[j2];
      if constexpr (!P2) {
        float e = 1.0f - fast_erfcf(az);
        S2p += (double)(qq*(z*e + __expf(-az*az)*IAS_F));
        acc += (double)(qq*e);
      } else {
        float dz = vzi - zv[j2];
        acc += (double)(qq*(K1_F*__expf(-az*az))*dz);
      }
    }
    atomicAdd(&g[tid*3+2], (-8.0*KE_C*PI_D/cell_area(cell))*acc);
    if constexpr (!P2) {
      #pragma unroll
      for (int m=1;m<64;m<<=1) S2p += __shfl_xor(S2p, m);
      if ((tid & 63) == 0) atomicAdd(&scal[cp*8+1], S2p);
    }
  }
}

// ---------------- finish1: energies, ffn, V ---------------------------------
__global__ void finish1_kernel(const double* gN, const double* scal, const float* q,
                               const float* cell, const int* im, const int* film,
                               double* V, float* out){
  int i = threadIdx.x;
  __shared__ double gsh[256*3];
  __shared__ double ffsh[12];
  double s0=0,s1=0,s2v=0;
  for (int c=0;c<NCPY;++c){
    const double* g = gN + c*768;
    s0 += g[i*3+0]; s1 += g[i*3+1]; s2v += g[i*3+2];
  }
  gsh[i*3+0]=s0; gsh[i*3+1]=s1; gsh[i*3+2]=s2v;
  __syncthreads();
  if (i < 12) {
    int mm = i/3, c = i%3;
    double s = 0.0;
    for (int a = 0; a < N_ATOMS; ++a)
      if (im[a] == mm && film[a] > 0) s -= gsh[a*3+c];
    ffsh[i] = s;
  }
  __syncthreads();
  {
    double mask = film[i] > 0 ? 1.0 : 0.0;
    int m = im[i];
    V[i*3+0] = mask*ffsh[m*3+0];
    V[i*3+1] = mask*ffsh[m*3+1];
    V[i*3+2] = mask*ffsh[m*3+2];
  }
  if (i == 0) {
    double qs = 0.0;
    for (int a = 0; a < N_ATOMS; ++a){ double qa=(double)q[a]; qs += qa*qa; }
    double area = cell_area(cell);
    double S=0,S2=0,RR=0,bm[4]={0,0,0,0};
    for (int c=0;c<NCPY;++c){
      S += scal[c*8+0]; S2 += scal[c*8+1]; RR += scal[c*8+2];
      for (int m=0;m<4;++m) bm[m] += scal[c*8+3+m];
    }
    double recip = KE_C*PI_D*(S/(2.0*area) - S2/area);
    double realE = 0.5*KE_C*RR;
    double selfE = -ALPHA_C/sqrt(PI_D)*qs*KE_C;
    double Ec = recip + realE + selfE;
    out[4] = (float)Ec;
    for (int m = 0; m < 4; ++m) {
      out[5+m] = (float)bm[m];
      out[m]   = (float)(Ec + bm[m]);
    }
  }
  if (i < 4) {
    double f0 = ffsh[i*3+0], f1 = ffsh[i*3+1], f2 = ffsh[i*3+2];
    out[9+i] = (float)(f0*f0 + f1*f1 + f2*f2);
  }
}

// ---------------- finish2: fng = -2 * segsum(mask * Hv) ---------------------
__global__ void finish2_kernel(const double* wN, const int* im, const int* film,
                               float* out){
  int i = threadIdx.x;
  __shared__ double gsh[256*3];
  double s0=0,s1=0,s2v=0;
  for (int c=0;c<NCPY;++c){
    const double* w = wN + c*768;
    s0 += w[i*3+0]; s1 += w[i*3+1]; s2v += w[i*3+2];
  }
  gsh[i*3+0]=s0; gsh[i*3+1]=s1; gsh[i*3+2]=s2v;
  __syncthreads();
  if (i < 12) {
    int mm = i/3, c = i%3;
    double s = 0.0;
    for (int a = 0; a < N_ATOMS; ++a)
      if (im[a] == mm && film[a] > 0) s += gsh[a*3+c];
    out[13+i] = (float)(-2.0*s);
  }
}

extern "C" void kernel_launch(void* const* d_in, const int* in_sizes, int n_in,
                              void* d_out, int out_size, void* d_ws, size_t ws_size,
                              hipStream_t stream){
  const float* R      = (const float*)d_in[0];
  const float* shiftv = (const float*)d_in[1];
  const float* q      = (const float*)d_in[2];
  const float* offs   = (const float*)d_in[3];
  const float* cell   = (const float*)d_in[4];
  const float* recipc = (const float*)d_in[5];
  const float* r0a    = (const float*)d_in[6];
  const float* na     = (const float*)d_in[7];
  const int*   ii     = (const int*)d_in[8];
  const int*   jj     = (const int*)d_in[9];
  const int*   im     = (const int*)d_in[10];
  const int*   film   = (const int*)d_in[11];
  float* out = (float*)d_out;

  double* ws   = (double*)d_ws;
  double* scal = ws;                    // NCPY x 8 = 256
  double* gN   = ws + 256;              // NCPY x 768
  double* wN   = ws + 256 + NCPY*768;   // NCPY x 768
  double* V    = ws + 256 + 2*NCPY*768; // 768 (written fully by finish1)
  float4* tab4  = (float4*)(ws + ZWORDS);        // 84*256 float4 = 344 KB
  float4* posf4 = tab4 + 84*256;                 // 256 float4

  hipLaunchKernelGGL(prep_kernel, dim3(NPREP), dim3(256), 0, stream,
                     R, shiftv, q, im, film, recipc, ws, tab4, posf4);
  hipLaunchKernelGGL((pass_kernel<0>), dim3(NBLK), dim3(256), 0, stream,
                     R, shiftv, q, offs, cell, recipc, r0a, na, ii, jj, im, film,
                     V, tab4, posf4, gN, scal);
  hipLaunchKernelGGL(finish1_kernel, dim3(1), dim3(256), 0, stream,
                     gN, scal, q, cell, im, film, V, out);
  hipLaunchKernelGGL((pass_kernel<1>), dim3(NBLK), dim3(256), 0, stream,
                     R, shiftv, q, offs, cell, recipc, r0a, na, ii, jj, im, film,
                     V, tab4, posf4, wN, scal);
  hipLaunchKernelGGL(finish2_kernel, dim3(1), dim3(256), 0, stream,
                     wN, im, film, out);
}

// Round 11
// 147.184 us; speedup vs baseline: 2.9974x; 1.2393x over previous
//
#include <hip/hip_runtime.h>

#define N_ATOMS 256
#define N_MOL 4
#define N_PAIRS 8192
#define KE_C 14.3996
#define ALPHA_C 0.3
#define CUTOFF_C 6.0

#define KS_B 1344   // 84 k x 16 i-chunks
#define REG_B 400   // 25 cells x 16 i-chunks (gradient)
#define REM_B 400   // 25 cells x 16 mol-pairs (Hessian M)
#define BO_B 32
#define S2_B 8
#define NBLK (KS_B+REG_B+REM_B+BO_B+S2_B)
#define NCPY 16
#define NPREP 85
#define ZWORDS (NCPY*8 + NCPY*768 + NCPY*96)   // scal + gN + Mg = 13952 doubles

constexpr double PI_D = 3.14159265358979323846;
#define AL_F 0.3f
#define TWOSQPI_F 1.12837917f
#define K1_F 0.33851375f    // TWOSQPI*ALPHA
#define IAS_F 1.8806320f    // 1/(ALPHA*sqrt(pi))
#define TWOA2_F 0.18f       // 2*ALPHA^2

__device__ __forceinline__ float fast_erfcf(float x){
  float ax = fabsf(x);
  float t = __fdividef(1.0f, fmaf(0.5f, ax, 1.0f));
  float p = 0.17087277f;
  p = fmaf(p, t, -0.82215223f);
  p = fmaf(p, t,  1.48851587f);
  p = fmaf(p, t, -1.13520398f);
  p = fmaf(p, t,  0.27886807f);
  p = fmaf(p, t, -0.18628806f);
  p = fmaf(p, t,  0.09678418f);
  p = fmaf(p, t,  0.37409196f);
  p = fmaf(p, t,  1.00002368f);
  p = fmaf(p, t, -1.26551223f);
  float ans = t*__expf(fmaf(-ax, ax, p));
  return x >= 0.0f ? ans : 2.0f - ans;
}

__device__ inline double ipown(double x, int e){
  double r = 1.0;
  while (e){ if (e & 1) r *= x; x *= x; e >>= 1; }
  return r;
}

__device__ inline double cell_area(const float* cell){
  double a0=cell[0], a1=cell[1], a2=cell[2];
  double b0=cell[3], b1=cell[4], b2=cell[5];
  double cx=a1*b2-a2*b1, cy=a2*b0-a0*b2, cz=a0*b1-a1*b0;
  return sqrt(cx*cx+cy*cy+cz*cz);
}
__device__ inline double posc(const float* R, const float* shiftv, const int* im,
                              const int* film, int a, int c){
  double mask = film[a] > 0 ? 1.0 : 0.0;
  return (double)R[a*3+c] + mask*(double)shiftv[im[a]*3+c];
}

// ---------------- prep: zero accumulators; build k-table + pos table --------
__global__ __launch_bounds__(256) void prep_kernel(
    const float* R, const float* shiftv, const float* q, const int* im,
    const int* film, const float* recipc, double* ws, float4* tab4, float4* posf4){
  int b = blockIdx.x, tid = threadIdx.x;
  { int w = b*256 + tid; if (w < ZWORDS) ws[w] = 0.0; }
  int a = tid;
  double xa = posc(R,shiftv,im,film,a,0);
  double ya = posc(R,shiftv,im,film,a,1);
  double za = posc(R,shiftv,im,film,a,2);
  if (b < 84) {
    double b0 = (double)(b/13 - 6), b1 = (double)(b%13 - 6);
    double TP = 2.0*PI_D;
    double h0 = TP*(b0*(double)recipc[0] + b1*(double)recipc[3]);
    double h1 = TP*(b0*(double)recipc[1] + b1*(double)recipc[4]);
    double h2 = TP*(b0*(double)recipc[2] + b1*(double)recipc[5]);
    double kap = sqrt(h0*h0 + h1*h1 + h2*h2);
    double phi = h0*xa + h1*ya + h2*za;
    double s, c; sincos(phi, &s, &c);
    double E = exp(kap*za);
    tab4[b*256+a] = make_float4((float)c, (float)s, (float)E, (float)(1.0/E));
  } else if (b == 84) {
    posf4[a] = make_float4((float)xa, (float)ya, (float)za, q[a]);
  }
}

// ---------------- single pass: gradient + energies + 12x12 Hessian M --------
__global__ __launch_bounds__(256) void pass_kernel(
    const float* R, const float* shiftv, const float* q, const float* offs,
    const float* cell, const float* recipc, const float* r0a, const float* na,
    const int* ii, const int* jj, const int* im, const int* film,
    const float4* tab4, const float4* posf4,
    double* gN, double* scal, double* Mg){
  __shared__ __align__(16) double shd[2048];   // 16 KB aliased
  float* f = (float*)shd;
  int b = blockIdx.x, tid = threadIdx.x;

  if (b < KS_B) {
    // =============== k-space: kk = b>>4, i-chunk ic = b&15 =================
    int kk = b >> 4, ic = b & 15;
    int mi = ic >> 2;
    int cp = (kk + 2*ic) & (NCPY-1);
    double* g = gN + cp*768;
    double b0 = (double)(kk/13 - 6), b1d = (double)(kk%13 - 6);
    double TP = 2.0*PI_D;
    double h0d = TP*(b0*(double)recipc[0] + b1d*(double)recipc[3]);
    double h1d = TP*(b0*(double)recipc[1] + b1d*(double)recipc[4]);
    double h2d = TP*(b0*(double)recipc[2] + b1d*(double)recipc[5]);
    double kapd = sqrt(h0d*h0d + h1d*h1d + h2d*h2d);
    float A    = (float)(kapd/(2.0*ALPHA_C));
    float ikap = (float)(1.0/kapd);
    float kapf = (float)kapd;
    float EA   = __expf(-A*A);
    float4* t4 = (float4*)f;          // f[0..1023]
    float* pzs = f + 1024;
    float* pqs = f + 1280;
    float* pms = f + 1536;            // ends f[1792) = shd dbl 896
    double* red2  = shd + 896;        // 16 x 27 = 432 dbl
    double* redsp = shd + 1344;       // 16 dbl
    {
      int a = tid;
      t4[a] = tab4[kk*256 + a];
      float4 p = posf4[a];
      pzs[a] = p.z; pqs[a] = p.w;
      pms[a] = film[a] > 0 ? 1.0f : 0.0f;
    }
    __syncthreads();
    int il = tid >> 4, jl = tid & 15;
    int i = ic*16 + il;
    float4 ti = t4[i];
    float ci=ti.x, si=ti.y, Ei=ti.z, iEi=ti.w;
    float zi=pzs[i], qi=pqs[i];
    double Sp=0.0, cmS=0.0, czS=0.0;
    double Aall0=0,Aall1=0,Aall2=0;
    double AmA0=0,AmA1=0,AmA2=0, AmB0=0,AmB1=0,AmB2=0;
    double AmC0=0,AmC1=0,AmC2=0, AmD0=0,AmD1=0,AmD2=0;
    #pragma unroll
    for (int tq=0; tq<4; ++tq){
      double g0=0,g1a=0,g2a=0;
      #pragma unroll
      for (int ts=0; ts<4; ++ts){
        int t = tq*4+ts;
        int jg = t*16 + jl;
        float4 tj = t4[jg];
        float z  = zi - pzs[jg];
        float az = AL_F*z;
        float u1 = A + az, u2 = A - az;
        float ec1 = fast_erfcf(u1), ec2 = fast_erfcf(u2);
        float ekz = Ei*tj.w, ikz = iEi*tj.z;
        float e1 = ekz*ec1, e2 = ikz*ec2;
        float cph = ci*tj.x + si*tj.y;
        float sph = si*tj.x - ci*tj.y;
        float em  = e1 - e2;
        float fF  = (e1+e2)*ikap;
        float pcf = cph*fF;
        float qq  = qi*pqs[jg];
        Sp  += (double)(qq*pcf);
        cmS += (double)(-2.0f*qq*sph*fF);
        czS += (double)( 2.0f*qq*cph*em);
        // Hessian scalars (skip self-term j==i)
        float mm = (jg != i) ? 1.0f : 0.0f;
        float Gs = TWOSQPI_F*EA*__expf(-az*az);
        float F2 = kapf*(e1+e2) - 2.0f*AL_F*Gs;
        float a1 = -qq*pcf*mm;
        float a2 = -qq*sph*em*mm;
        float a3 =  qq*cph*F2*mm;
        Aall0 += (double)a1; Aall1 += (double)a2; Aall2 += (double)a3;
        float mj_ = pms[jg];
        g0 += (double)(a1*mj_); g1a += (double)(a2*mj_); g2a += (double)(a3*mj_);
      }
      if      (tq==0){ AmA0+=g0; AmA1+=g1a; AmA2+=g2a; }
      else if (tq==1){ AmB0+=g0; AmB1+=g1a; AmB2+=g2a; }
      else if (tq==2){ AmC0+=g0; AmC1+=g1a; AmC2+=g2a; }
      else           { AmD0+=g0; AmD1+=g1a; AmD2+=g2a; }
    }
    #pragma unroll
    for (int m=1;m<16;m<<=1){
      Sp += __shfl_xor(Sp, m); cmS += __shfl_xor(cmS, m); czS += __shfl_xor(czS, m);
      Aall0+=__shfl_xor(Aall0,m); Aall1+=__shfl_xor(Aall1,m); Aall2+=__shfl_xor(Aall2,m);
      AmA0+=__shfl_xor(AmA0,m); AmA1+=__shfl_xor(AmA1,m); AmA2+=__shfl_xor(AmA2,m);
      AmB0+=__shfl_xor(AmB0,m); AmB1+=__shfl_xor(AmB1,m); AmB2+=__shfl_xor(AmB2,m);
      AmC0+=__shfl_xor(AmC0,m); AmC1+=__shfl_xor(AmC1,m); AmC2+=__shfl_xor(AmC2,m);
      AmD0+=__shfl_xor(AmD0,m); AmD1+=__shfl_xor(AmD1,m); AmD2+=__shfl_xor(AmD2,m);
    }
    double gsc = 4.0*KE_C*PI_D/cell_area(cell);
    if (jl == 0){
      atomicAdd(&g[i*3+0], gsc*(h0d*cmS));
      atomicAdd(&g[i*3+1], gsc*(h1d*cmS));
      atomicAdd(&g[i*3+2], gsc*(h2d*cmS + czS));
      redsp[il] = Sp;
      double msi = (double)pms[i];
      double* r = red2 + il*27;
      r[0]=msi*Aall0; r[1]=msi*Aall1; r[2]=msi*Aall2;
      r[3]=AmA0; r[4]=AmA1; r[5]=AmA2;
      r[6]=AmB0; r[7]=AmB1; r[8]=AmB2;
      r[9]=AmC0; r[10]=AmC1; r[11]=AmC2;
      r[12]=AmD0; r[13]=AmD1; r[14]=AmD2;
      r[15]=msi*AmA0; r[16]=msi*AmA1; r[17]=msi*AmA2;
      r[18]=msi*AmB0; r[19]=msi*AmB1; r[20]=msi*AmB2;
      r[21]=msi*AmC0; r[22]=msi*AmC1; r[23]=msi*AmC2;
      r[24]=msi*AmD0; r[25]=msi*AmD1; r[26]=msi*AmD2;
    }
    __syncthreads();
    if (tid == 0){
      double s = 0.0;
      #pragma unroll
      for (int u=0;u<16;++u) s += redsp[u];
      atomicAdd(&scal[cp*8+0], 2.0*s);
    }
    if (tid < 9){
      int s = tid;
      int col, tm0, tm1; double sgn;
      if (s == 0){ col = 0; tm0 = mi; tm1 = mi; sgn = 1.0; }
      else if (s < 5){ int mjs = s-1; col = 3+3*mjs; tm0 = mjs; tm1 = mjs; sgn = 1.0; }
      else { int mjs = s-5; col = 15+3*mjs; tm0 = mi; tm1 = mjs; sgn = -1.0; }
      double S1=0,S2v=0,S3=0;
      for (int u=0;u<16;++u){
        S1 += red2[u*27+col]; S2v += red2[u*27+col+1]; S3 += red2[u*27+col+2];
      }
      double cS = sgn*gsc;
      double exx = cS*(S1*h0d*h0d);
      double exy = cS*(S1*h0d*h1d);
      double exz = cS*(S1*h0d*h2d + S2v*h0d);
      double eyy = cS*(S1*h1d*h1d);
      double eyz = cS*(S1*h1d*h2d + S2v*h1d);
      double ezz = cS*(S1*h2d*h2d + 2.0*S2v*h2d + S3);
      double* M = Mg + cp*96 + (tm0*4+tm1)*6;
      atomicAdd(&M[0], exx); atomicAdd(&M[1], exy); atomicAdd(&M[2], exz);
      atomicAdd(&M[3], eyy); atomicAdd(&M[4], eyz); atomicAdd(&M[5], ezz);
    }
  } else if (b < KS_B + REG_B) {
    // =============== real-space gradient + energy ==========================
    int r = b - KS_B; int nn = r >> 4, ic = r & 15;
    int cp = (nn + 2*ic) & (NCPY-1);
    double* g = gN + cp*768;
    double n0 = (double)(nn/5 - 2), n1 = (double)(nn%5 - 2);
    float a0 = (float)(n0*(double)cell[0] + n1*(double)cell[3]);
    float a1c = (float)(n0*(double)cell[1] + n1*(double)cell[4]);
    float a2c = (float)(n0*(double)cell[2] + n1*(double)cell[5]);
    float *px=f, *py=f+256, *pz=f+512, *pq=f+768;
    double* redg = shd + 896;
    {
      int a = tid;
      float4 p = posf4[a];
      px[a]=p.x; py[a]=p.y; pz[a]=p.z; pq[a]=p.w;
    }
    __syncthreads();
    int il = tid >> 4, jl = tid & 15;
    int i = ic*16 + il;
    float xi=px[i], yi=py[i], zi=pz[i], qi=pq[i];
    double gx=0,gy=0,gz=0,Rp=0;
    #pragma unroll 4
    for (int t=0;t<16;++t){
      int j = t*16 + jl;
      float rx = xi - px[j] + a0;
      float ry = yi - py[j] + a1c;
      float rz = zi - pz[j] + a2c;
      float dsq = rx*rx+ry*ry+rz*rz;
      if (dsq > 0.0f){
        float d = sqrtf(dsq);
        float invd = __fdividef(1.0f, d);
        float ad = AL_F*d;
        float ec = fast_erfcf(ad);
        float ex = __expf(-ad*ad);
        float qq = qi*pq[j];
        float P  = -(K1_F*ex*invd + ec*invd*invd);
        float C  = qq*P*invd;
        Rp += (double)(qq*ec*invd);
        gx += (double)(C*rx); gy += (double)(C*ry); gz += (double)(C*rz);
      }
    }
    #pragma unroll
    for (int m=1;m<16;m<<=1){
      gx += __shfl_xor(gx, m); gy += __shfl_xor(gy, m); gz += __shfl_xor(gz, m);
      Rp += __shfl_xor(Rp, m);
    }
    if (jl == 0){
      atomicAdd(&g[i*3+0], 4.0*KE_C*gx);
      atomicAdd(&g[i*3+1], 4.0*KE_C*gy);
      atomicAdd(&g[i*3+2], 4.0*KE_C*gz);
      redg[il] = Rp;
    }
    __syncthreads();
    if (tid == 0){
      double s = 0.0;
      #pragma unroll
      for (int u=0;u<16;++u) s += redg[u];
      atomicAdd(&scal[cp*8+2], s);
    }
  } else if (b < KS_B + REG_B + REM_B) {
    // =============== real-space Hessian M: (cell, mi, mj) blocks ===========
    int rb = b - (KS_B + REG_B);
    int nn = rb >> 4, mp = rb & 15;
    int mi = mp >> 2, mjm = mp & 3;
    int cp = (nn + mp) & (NCPY-1);
    double n0 = (double)(nn/5 - 2), n1 = (double)(nn%5 - 2);
    float a0 = (float)(n0*(double)cell[0] + n1*(double)cell[3]);
    float a1c = (float)(n0*(double)cell[1] + n1*(double)cell[4]);
    float a2c = (float)(n0*(double)cell[2] + n1*(double)cell[5]);
    float *px=f, *py=f+256, *pz=f+512, *pq=f+768, *pm=f+1024; // 640 dbl
    double* red2m = shd + 640;   // 64 x 21 = 1344 dbl -> ends 1984
    double* redS  = shd + 1984;  // 21 dbl
    {
      int a = tid;
      float4 p = posf4[a];
      px[a]=p.x; py[a]=p.y; pz[a]=p.z; pq[a]=p.w;
      pm[a] = film[a] > 0 ? 1.0f : 0.0f;
    }
    __syncthreads();
    int il = tid >> 2, jl = tid & 3;
    int i = mi*64 + il;
    float xi=px[i], yi=py[i], zi=pz[i], qi=pq[i];
    double msi = (double)pm[i];
    double u0=0,u1v=0,u2v=0,u3=0,u4=0,u5=0,u6=0;
    double m0=0,m1v=0,m2v=0,m3=0,m4=0,m5=0,m6=0;
    #pragma unroll 4
    for (int t=0;t<16;++t){
      int jg = mjm*64 + t*4 + jl;
      float rx = xi - px[jg] + a0;
      float ry = yi - py[jg] + a1c;
      float rz = zi - pz[jg] + a2c;
      float dsq = rx*rx+ry*ry+rz*rz;
      if (dsq > 0.0f && jg != i){
        float d = sqrtf(dsq);
        float invd = __fdividef(1.0f, d);
        float invd2 = invd*invd;
        float ad = AL_F*d;
        float ec = fast_erfcf(ad);
        float ex = __expf(-ad*ad);
        float qq = qi*pq[jg];
        float P  = -(K1_F*ex*invd + ec*invd2);
        float b1 = qq*P*invd;
        float bW = qq*invd*( K1_F*ex*(TWOA2_F + 3.0f*invd2)*invd + 3.0f*ec*invd2*invd2 );
        float w1=bW*rx*rx, w2=bW*rx*ry, w3=bW*rx*rz, w4=bW*ry*ry, w5=bW*ry*rz, w6=bW*rz*rz;
        u0+=(double)b1; u1v+=(double)w1; u2v+=(double)w2; u3+=(double)w3;
        u4+=(double)w4; u5+=(double)w5; u6+=(double)w6;
        float mj_ = pm[jg];
        m0+=(double)(b1*mj_); m1v+=(double)(w1*mj_); m2v+=(double)(w2*mj_);
        m3+=(double)(w3*mj_); m4+=(double)(w4*mj_); m5+=(double)(w5*mj_); m6+=(double)(w6*mj_);
      }
    }
    #pragma unroll
    for (int m=1;m<4;m<<=1){
      u0+=__shfl_xor(u0,m); u1v+=__shfl_xor(u1v,m); u2v+=__shfl_xor(u2v,m);
      u3+=__shfl_xor(u3,m); u4+=__shfl_xor(u4,m); u5+=__shfl_xor(u5,m); u6+=__shfl_xor(u6,m);
      m0+=__shfl_xor(m0,m); m1v+=__shfl_xor(m1v,m); m2v+=__shfl_xor(m2v,m);
      m3+=__shfl_xor(m3,m); m4+=__shfl_xor(m4,m); m5+=__shfl_xor(m5,m); m6+=__shfl_xor(m6,m);
    }
    if (jl == 0){
      double* rr = red2m + il*21;
      rr[0]=msi*u0; rr[1]=msi*u1v; rr[2]=msi*u2v; rr[3]=msi*u3;
      rr[4]=msi*u4; rr[5]=msi*u5; rr[6]=msi*u6;
      rr[7]=m0; rr[8]=m1v; rr[9]=m2v; rr[10]=m3; rr[11]=m4; rr[12]=m5; rr[13]=m6;
      rr[14]=msi*m0; rr[15]=msi*m1v; rr[16]=msi*m2v; rr[17]=msi*m3;
      rr[18]=msi*m4; rr[19]=msi*m5; rr[20]=msi*m6;
    }
    __syncthreads();
    if (tid < 21){
      double s = 0.0;
      for (int u=0;u<64;++u) s += red2m[u*21+tid];
      redS[tid] = s;
    }
    __syncthreads();
    if (tid < 18){
      int slot = tid/6, e = tid%6;
      const double* S = redS + slot*7;
      double val;
      if (e==0) val = S[0] + S[1];
      else if (e==1) val = S[2];
      else if (e==2) val = S[3];
      else if (e==3) val = S[0] + S[4];
      else if (e==4) val = S[5];
      else val = S[0] + S[6];
      double sgn = (slot==2) ? -1.0 : 1.0;
      int tm0 = (slot==1) ? mjm : mi;
      int tm1 = (slot==0) ? mi : mjm;
      atomicAdd(&Mg[cp*96 + (tm0*4+tm1)*6 + e], sgn*2.0*KE_C*val);
    }
  } else if (b < KS_B + REG_B + REM_B + BO_B) {
    // =============== Born: gradient + energy + M ===========================
    int bb = b - (KS_B + REG_B + REM_B);
    int cp = bb & (NCPY-1);
    double* g = gN + cp*768;
    int p = bb*256 + tid;
    int ai = ii[p], aj = jj[p];
    double rx = posc(R,shiftv,im,film,aj,0) - posc(R,shiftv,im,film,ai,0) + (double)offs[p*3+0];
    double ry = posc(R,shiftv,im,film,aj,1) - posc(R,shiftv,im,film,ai,1) + (double)offs[p*3+1];
    double rz = posc(R,shiftv,im,film,aj,2) - posc(R,shiftv,im,film,ai,2) + (double)offs[p*3+2];
    double dsq = rx*rx + ry*ry + rz*rz;
    double d = sqrt(dsq);
    double y = 0.0;
    if (d < CUTOFF_C) {
      double qq = fabs((double)q[ai]*(double)q[aj]);
      int    ni = (int)(na[p] + 0.5f);
      double n  = (double)ni;
      double B  = qq * ipown((double)r0a[p], ni-1) / n;
      double dmn = ipown(1.0/d, ni);
      y = 0.5*KE_C*B*(dmn - ipown(1.0/CUTOFF_C, ni));
      double c = (-0.5*KE_C*n*B) * (dmn / dsq);
      atomicAdd(&g[aj*3+0],  c*rx);
      atomicAdd(&g[aj*3+1],  c*ry);
      atomicAdd(&g[aj*3+2],  c*rz);
      atomicAdd(&g[ai*3+0], -c*rx);
      atomicAdd(&g[ai*3+1], -c*ry);
      atomicAdd(&g[ai*3+2], -c*rz);
      // Hessian M
      bool fi = film[ai] > 0, fj = film[aj] > 0;
      if (fi || fj){
        double b2 = -c*(n+2.0)/dsq;
        double E0 = c + b2*rx*rx, E1 = b2*rx*ry, E2 = b2*rx*rz;
        double E3 = c + b2*ry*ry, E4 = b2*ry*rz, E5 = c + b2*rz*rz;
        double* M = Mg + cp*96;
        int mi_ = im[ai], mj_ = im[aj];
        if (fi){
          double* t = M + (mi_*4+mi_)*6;
          atomicAdd(&t[0],E0); atomicAdd(&t[1],E1); atomicAdd(&t[2],E2);
          atomicAdd(&t[3],E3); atomicAdd(&t[4],E4); atomicAdd(&t[5],E5);
        }
        if (fj){
          double* t = M + (mj_*4+mj_)*6;
          atomicAdd(&t[0],E0); atomicAdd(&t[1],E1); atomicAdd(&t[2],E2);
          atomicAdd(&t[3],E3); atomicAdd(&t[4],E4); atomicAdd(&t[5],E5);
        }
        if (fi && fj){
          if (mi_ != mj_){
            double* t = M + (mi_*4+mj_)*6;
            atomicAdd(&t[0],-E0); atomicAdd(&t[1],-E1); atomicAdd(&t[2],-E2);
            atomicAdd(&t[3],-E3); atomicAdd(&t[4],-E4); atomicAdd(&t[5],-E5);
            double* u = M + (mj_*4+mi_)*6;
            atomicAdd(&u[0],-E0); atomicAdd(&u[1],-E1); atomicAdd(&u[2],-E2);
            atomicAdd(&u[3],-E3); atomicAdd(&u[4],-E4); atomicAdd(&u[5],-E5);
          } else {
            double* t = M + (mi_*4+mi_)*6;
            atomicAdd(&t[0],-2.0*E0); atomicAdd(&t[1],-2.0*E1); atomicAdd(&t[2],-2.0*E2);
            atomicAdd(&t[3],-2.0*E3); atomicAdd(&t[4],-2.0*E4); atomicAdd(&t[5],-2.0*E5);
          }
        }
      }
    }
    {
      int myMol = im[ai];
      #pragma unroll
      for (int mm=0; mm<4; ++mm){
        double v = (myMol==mm) ? y : 0.0;
        for (int off=32; off; off>>=1) v += __shfl_down(v, off, 64);
        if ((tid & 63) == 0 && v != 0.0)
          atomicAdd(&scal[cp*8+3+mm], v);
      }
    }
  } else {
    // =============== S2: gradient + energy + M (zz only) ===================
    int jc = b - (KS_B + REG_B + REM_B + BO_B);
    int cp = (jc*2+1) & (NCPY-1);
    double* g = gN + cp*768;
    float *zz=f, *zq=f+32, *zm=f+64;
    double* redsp = shd + 896;
    if (tid < 32) {
      int j = jc*32 + tid;
      float4 p = posf4[j];
      zz[tid] = p.z; zq[tid] = p.w;
      zm[tid] = film[j] > 0 ? 1.0f : 0.0f;
    }
    __syncthreads();
    float4 pi = posf4[tid];
    float ziv = pi.z, qi = pi.w;
    double msi = film[tid] > 0 ? 1.0 : 0.0;
    int mi = tid >> 6, mjs2 = jc >> 1;
    double acc = 0.0, S2p = 0.0;
    double uii=0.0, ujj=0.0, uij=0.0;
    for (int j2=0;j2<32;++j2){
      int jg = jc*32 + j2;
      float z = ziv - zz[j2];
      float az = AL_F*z;
      float qq = qi*zq[j2];
      float ex = __expf(-az*az);
      float e = 1.0f - fast_erfcf(az);
      S2p += (double)(qq*(z*e + ex*IAS_F));
      acc += (double)(qq*e);
      if (jg != tid){
        double gpp = (double)(qq*K1_F*ex);
        double mj_ = (double)zm[j2];
        uii += msi*gpp;
        ujj += mj_*gpp;
        uij += msi*mj_*gpp;
      }
    }
    double area = cell_area(cell);
    atomicAdd(&g[tid*3+2], (-8.0*KE_C*PI_D/area)*acc);
    #pragma unroll
    for (int m=1;m<64;m<<=1){
      S2p += __shfl_xor(S2p, m);
      uii += __shfl_xor(uii, m); ujj += __shfl_xor(ujj, m); uij += __shfl_xor(uij, m);
    }
    if ((tid & 63) == 0){
      atomicAdd(&scal[cp*8+1], S2p);
      double Cs = -4.0*KE_C*PI_D/area;
      atomicAdd(&Mg[cp*96 + (mi*4+mi)*6 + 5],     Cs*uii);
      atomicAdd(&Mg[cp*96 + (mjs2*4+mjs2)*6 + 5], Cs*ujj);
      atomicAdd(&Mg[cp*96 + (mi*4+mjs2)*6 + 5],  -Cs*uij);
    }
  }
}

// ---------------- finish: energies, ffn, fng = -2 M ff ----------------------
__global__ void finish_kernel(const double* gN, const double* scal, const double* Mg,
                              const float* q, const float* cell, const int* im,
                              const int* film, float* out){
  __shared__ double shd[1024];
  double* gsh  = shd;        // 768
  double* ffsh = shd + 768;  // 12
  double* Msh  = shd + 800;  // 96
  int i = threadIdx.x;
  double s0=0,s1=0,s2v=0;
  for (int c=0;c<NCPY;++c){
    const double* g = gN + c*768;
    s0 += g[i*3+0]; s1 += g[i*3+1]; s2v += g[i*3+2];
  }
  gsh[i*3+0]=s0; gsh[i*3+1]=s1; gsh[i*3+2]=s2v;
  if (i < 96){
    double s = 0.0;
    for (int c=0;c<NCPY;++c) s += Mg[c*96 + i];
    Msh[i] = s;
  }
  __syncthreads();
  if (i < 12) {
    int mm = i/3, c = i%3;
    double s = 0.0;
    for (int a = 0; a < N_ATOMS; ++a)
      if (im[a] == mm && film[a] > 0) s -= gsh[a*3+c];
    ffsh[i] = s;
  }
  __syncthreads();
  if (i == 0) {
    double qs = 0.0;
    for (int a = 0; a < N_ATOMS; ++a){ double qa=(double)q[a]; qs += qa*qa; }
    double area = cell_area(cell);
    double S=0,S2=0,RR=0,bm[4]={0,0,0,0};
    for (int c=0;c<NCPY;++c){
      S += scal[c*8+0]; S2 += scal[c*8+1]; RR += scal[c*8+2];
      for (int m=0;m<4;++m) bm[m] += scal[c*8+3+m];
    }
    double recip = KE_C*PI_D*(S/(2.0*area) - S2/area);
    double realE = 0.5*KE_C*RR;
    double selfE = -ALPHA_C/sqrt(PI_D)*qs*KE_C;
    double Ec = recip + realE + selfE;
    out[4] = (float)Ec;
    for (int m = 0; m < 4; ++m) {
      out[5+m] = (float)bm[m];
      out[m]   = (float)(Ec + bm[m]);
    }
  }
  if (i < 4) {
    double f0 = ffsh[i*3+0], f1 = ffsh[i*3+1], f2 = ffsh[i*3+2];
    out[9+i] = (float)(f0*f0 + f1*f1 + f2*f2);
  }
  if (i < 12) {
    int m = i/3, c = i%3;
    const int sidx[3][3] = {{0,1,2},{1,3,4},{2,4,5}};
    double s = 0.0;
    for (int m2=0;m2<4;++m2)
      for (int c2=0;c2<3;++c2)
        s += Msh[(m*4+m2)*6 + sidx[c][c2]] * ffsh[m2*3+c2];
    out[13+i] = (float)(-2.0*s);
  }
}

extern "C" void kernel_launch(void* const* d_in, const int* in_sizes, int n_in,
                              void* d_out, int out_size, void* d_ws, size_t ws_size,
                              hipStream_t stream){
  const float* R      = (const float*)d_in[0];
  const float* shiftv = (const float*)d_in[1];
  const float* q      = (const float*)d_in[2];
  const float* offs   = (const float*)d_in[3];
  const float* cell   = (const float*)d_in[4];
  const float* recipc = (const float*)d_in[5];
  const float* r0a    = (const float*)d_in[6];
  const float* na     = (const float*)d_in[7];
  const int*   ii     = (const int*)d_in[8];
  const int*   jj     = (const int*)d_in[9];
  const int*   im     = (const int*)d_in[10];
  const int*   film   = (const int*)d_in[11];
  float* out = (float*)d_out;

  double* ws   = (double*)d_ws;
  double* scal = ws;                         // NCPY*8   = 128
  double* gN   = ws + NCPY*8;                // NCPY*768 = 12288
  double* Mg   = ws + NCPY*8 + NCPY*768;     // NCPY*96  = 1536
  float4* tab4  = (float4*)(ws + ZWORDS);    // 84*256 float4
  float4* posf4 = tab4 + 84*256;             // 256 float4

  hipLaunchKernelGGL(prep_kernel, dim3(NPREP), dim3(256), 0, stream,
                     R, shiftv, q, im, film, recipc, ws, tab4, posf4);
  hipLaunchKernelGGL(pass_kernel, dim3(NBLK), dim3(256), 0, stream,
                     R, shiftv, q, offs, cell, recipc, r0a, na, ii, jj, im, film,
                     tab4, posf4, gN, scal, Mg);
  hipLaunchKernelGGL(finish_kernel, dim3(1), dim3(256), 0, stream,
                     gN, scal, Mg, q, cell, im, film, out);
}

// Round 12
// 141.499 us; speedup vs baseline: 3.1178x; 1.0402x over previous
//
#include <hip/hip_runtime.h>

#define N_ATOMS 256
#define N_MOL 4
#define N_PAIRS 8192
#define KE_C 14.3996
#define ALPHA_C 0.3
#define CUTOFF_C 6.0

#define KS_B 1344   // 84 k x 16 i-chunks
#define REG_B 400   // 25 cells x 16 i-chunks (gradient)
#define REM_B 400   // 25 cells x 16 mol-pairs (Hessian M)
#define BO_B 32
#define S2_B 8
#define NBLK (KS_B+REG_B+REM_B+BO_B+S2_B)
#define NCPY 16
#define NPREP 85
#define ZWORDS (NCPY*8 + NCPY*768 + NCPY*96)   // scal + gN + Mg = 13952 doubles

constexpr double PI_D = 3.14159265358979323846;
#define AL_F 0.3f
#define TWOSQPI_F 1.12837917f
#define K1_F 0.33851375f    // TWOSQPI*ALPHA
#define IAS_F 1.8806320f    // 1/(ALPHA*sqrt(pi))
#define TWOA2_F 0.18f       // 2*ALPHA^2

__device__ __forceinline__ float fast_erfcf(float x){
  float ax = fabsf(x);
  float t = __fdividef(1.0f, fmaf(0.5f, ax, 1.0f));
  float p = 0.17087277f;
  p = fmaf(p, t, -0.82215223f);
  p = fmaf(p, t,  1.48851587f);
  p = fmaf(p, t, -1.13520398f);
  p = fmaf(p, t,  0.27886807f);
  p = fmaf(p, t, -0.18628806f);
  p = fmaf(p, t,  0.09678418f);
  p = fmaf(p, t,  0.37409196f);
  p = fmaf(p, t,  1.00002368f);
  p = fmaf(p, t, -1.26551223f);
  float ans = t*__expf(fmaf(-ax, ax, p));
  return x >= 0.0f ? ans : 2.0f - ans;
}

__device__ inline double ipown(double x, int e){
  double r = 1.0;
  while (e){ if (e & 1) r *= x; x *= x; e >>= 1; }
  return r;
}

__device__ inline double cell_area(const float* cell){
  double a0=cell[0], a1=cell[1], a2=cell[2];
  double b0=cell[3], b1=cell[4], b2=cell[5];
  double cx=a1*b2-a2*b1, cy=a2*b0-a0*b2, cz=a0*b1-a1*b0;
  return sqrt(cx*cx+cy*cy+cz*cz);
}
__device__ inline double posc(const float* R, const float* shiftv, const int* im,
                              const int* film, int a, int c){
  double mask = film[a] > 0 ? 1.0 : 0.0;
  return (double)R[a*3+c] + mask*(double)shiftv[im[a]*3+c];
}

// ---------------- prep: zero accumulators; build k-table + pos table --------
__global__ __launch_bounds__(256) void prep_kernel(
    const float* R, const float* shiftv, const float* q, const int* im,
    const int* film, const float* recipc, double* ws, float4* tab4, float4* posf4){
  int b = blockIdx.x, tid = threadIdx.x;
  { int w = b*256 + tid; if (w < ZWORDS) ws[w] = 0.0; }
  int a = tid;
  double xa = posc(R,shiftv,im,film,a,0);
  double ya = posc(R,shiftv,im,film,a,1);
  double za = posc(R,shiftv,im,film,a,2);
  if (b < 84) {
    double b0 = (double)(b/13 - 6), b1 = (double)(b%13 - 6);
    double TP = 2.0*PI_D;
    double h0 = TP*(b0*(double)recipc[0] + b1*(double)recipc[3]);
    double h1 = TP*(b0*(double)recipc[1] + b1*(double)recipc[4]);
    double h2 = TP*(b0*(double)recipc[2] + b1*(double)recipc[5]);
    double kap = sqrt(h0*h0 + h1*h1 + h2*h2);
    double phi = h0*xa + h1*ya + h2*za;
    double s, c; sincos(phi, &s, &c);
    double E = exp(kap*za);
    tab4[b*256+a] = make_float4((float)c, (float)s, (float)E, (float)(1.0/E));
  } else if (b == 84) {
    posf4[a] = make_float4((float)xa, (float)ya, (float)za, q[a]);
  }
}

// ---------------- single pass: gradient + energies + 12x12 Hessian M --------
__global__ __launch_bounds__(256) void pass_kernel(
    const float* R, const float* shiftv, const float* q, const float* offs,
    const float* cell, const float* recipc, const float* r0a, const float* na,
    const int* ii, const int* jj, const int* im, const int* film,
    const float4* tab4, const float4* posf4,
    double* gN, double* scal, double* Mg){
  __shared__ __align__(16) double shd[2048];   // 16 KB aliased
  float* f = (float*)shd;
  int b = blockIdx.x, tid = threadIdx.x;

  if (b < KS_B) {
    // =============== k-space: kk = b>>4, i-chunk ic = b&15 =================
    int kk = b >> 4, ic = b & 15;
    int mi = ic >> 2;
    int cp = (kk + 2*ic) & (NCPY-1);
    double* g = gN + cp*768;
    double b0 = (double)(kk/13 - 6), b1d = (double)(kk%13 - 6);
    double TP = 2.0*PI_D;
    double h0d = TP*(b0*(double)recipc[0] + b1d*(double)recipc[3]);
    double h1d = TP*(b0*(double)recipc[1] + b1d*(double)recipc[4]);
    double h2d = TP*(b0*(double)recipc[2] + b1d*(double)recipc[5]);
    double kapd = sqrt(h0d*h0d + h1d*h1d + h2d*h2d);
    float A    = (float)(kapd/(2.0*ALPHA_C));
    float ikap = (float)(1.0/kapd);
    float kapf = (float)kapd;
    float EA   = __expf(-A*A);
    float4* t4 = (float4*)f;          // f[0..1023]
    float* pzs = f + 1024;
    float* pqs = f + 1280;
    float* pms = f + 1536;            // ends f[1792) = shd dbl 896
    double* red2  = shd + 896;        // 16 x 27 = 432 dbl
    double* redsp = shd + 1344;       // 16 dbl
    {
      int a = tid;
      t4[a] = tab4[kk*256 + a];
      float4 p = posf4[a];
      pzs[a] = p.z; pqs[a] = p.w;
      pms[a] = film[a] > 0 ? 1.0f : 0.0f;
    }
    __syncthreads();
    int il = tid >> 4, jl = tid & 15;
    int i = ic*16 + il;
    float4 ti = t4[i];
    float ci=ti.x, si=ti.y, Ei=ti.z, iEi=ti.w;
    float zi=pzs[i], qi=pqs[i];
    double Sp=0.0, cmS=0.0, czS=0.0;
    double Aall0=0,Aall1=0,Aall2=0;
    double AmA0=0,AmA1=0,AmA2=0, AmB0=0,AmB1=0,AmB2=0;
    double AmC0=0,AmC1=0,AmC2=0, AmD0=0,AmD1=0,AmD2=0;
    #pragma unroll
    for (int tq=0; tq<4; ++tq){
      // fp32 chunk accumulators (promoted to fp64 once per 4-iter chunk)
      float fSp=0.f, fcm=0.f, fcz=0.f;
      float fA0=0.f, fA1=0.f, fA2=0.f;
      float fg0=0.f, fg1=0.f, fg2=0.f;
      #pragma unroll
      for (int ts=0; ts<4; ++ts){
        int t = tq*4+ts;
        int jg = t*16 + jl;
        float4 tj = t4[jg];
        float z  = zi - pzs[jg];
        float az = AL_F*z;
        float u1 = A + az, u2 = A - az;
        float ec1 = fast_erfcf(u1), ec2 = fast_erfcf(u2);
        float ekz = Ei*tj.w, ikz = iEi*tj.z;
        float e1 = ekz*ec1, e2 = ikz*ec2;
        float cph = ci*tj.x + si*tj.y;
        float sph = si*tj.x - ci*tj.y;
        float em  = e1 - e2;
        float fF  = (e1+e2)*ikap;
        float pcf = cph*fF;
        float qq  = qi*pqs[jg];
        fSp = fmaf(qq, pcf, fSp);
        fcm = fmaf(-2.0f*qq, sph*fF, fcm);
        fcz = fmaf( 2.0f*qq, cph*em, fcz);
        // Hessian scalars (skip self-term j==i)
        float mm = (jg != i) ? 1.0f : 0.0f;
        float Gs = TWOSQPI_F*EA*__expf(-az*az);
        float F2 = kapf*(e1+e2) - 2.0f*AL_F*Gs;
        float a1 = -qq*pcf*mm;
        float a2 = -qq*sph*em*mm;
        float a3 =  qq*cph*F2*mm;
        fA0 += a1; fA1 += a2; fA2 += a3;
        float mj_ = pms[jg];
        fg0 = fmaf(a1, mj_, fg0); fg1 = fmaf(a2, mj_, fg1); fg2 = fmaf(a3, mj_, fg2);
      }
      Sp += (double)fSp; cmS += (double)fcm; czS += (double)fcz;
      Aall0 += (double)fA0; Aall1 += (double)fA1; Aall2 += (double)fA2;
      if      (tq==0){ AmA0=(double)fg0; AmA1=(double)fg1; AmA2=(double)fg2; }
      else if (tq==1){ AmB0=(double)fg0; AmB1=(double)fg1; AmB2=(double)fg2; }
      else if (tq==2){ AmC0=(double)fg0; AmC1=(double)fg1; AmC2=(double)fg2; }
      else           { AmD0=(double)fg0; AmD1=(double)fg1; AmD2=(double)fg2; }
    }
    #pragma unroll
    for (int m=1;m<16;m<<=1){
      Sp += __shfl_xor(Sp, m); cmS += __shfl_xor(cmS, m); czS += __shfl_xor(czS, m);
      Aall0+=__shfl_xor(Aall0,m); Aall1+=__shfl_xor(Aall1,m); Aall2+=__shfl_xor(Aall2,m);
      AmA0+=__shfl_xor(AmA0,m); AmA1+=__shfl_xor(AmA1,m); AmA2+=__shfl_xor(AmA2,m);
      AmB0+=__shfl_xor(AmB0,m); AmB1+=__shfl_xor(AmB1,m); AmB2+=__shfl_xor(AmB2,m);
      AmC0+=__shfl_xor(AmC0,m); AmC1+=__shfl_xor(AmC1,m); AmC2+=__shfl_xor(AmC2,m);
      AmD0+=__shfl_xor(AmD0,m); AmD1+=__shfl_xor(AmD1,m); AmD2+=__shfl_xor(AmD2,m);
    }
    double gsc = 4.0*KE_C*PI_D/cell_area(cell);
    if (jl == 0){
      atomicAdd(&g[i*3+0], gsc*(h0d*cmS));
      atomicAdd(&g[i*3+1], gsc*(h1d*cmS));
      atomicAdd(&g[i*3+2], gsc*(h2d*cmS + czS));
      redsp[il] = Sp;
      double msi = (double)pms[i];
      double* r = red2 + il*27;
      r[0]=msi*Aall0; r[1]=msi*Aall1; r[2]=msi*Aall2;
      r[3]=AmA0; r[4]=AmA1; r[5]=AmA2;
      r[6]=AmB0; r[7]=AmB1; r[8]=AmB2;
      r[9]=AmC0; r[10]=AmC1; r[11]=AmC2;
      r[12]=AmD0; r[13]=AmD1; r[14]=AmD2;
      r[15]=msi*AmA0; r[16]=msi*AmA1; r[17]=msi*AmA2;
      r[18]=msi*AmB0; r[19]=msi*AmB1; r[20]=msi*AmB2;
      r[21]=msi*AmC0; r[22]=msi*AmC1; r[23]=msi*AmC2;
      r[24]=msi*AmD0; r[25]=msi*AmD1; r[26]=msi*AmD2;
    }
    __syncthreads();
    if (tid == 0){
      double s = 0.0;
      #pragma unroll
      for (int u=0;u<16;++u) s += redsp[u];
      atomicAdd(&scal[cp*8+0], 2.0*s);
    }
    if (tid < 9){
      int s = tid;
      int col, tm0, tm1; double sgn;
      if (s == 0){ col = 0; tm0 = mi; tm1 = mi; sgn = 1.0; }
      else if (s < 5){ int mjs = s-1; col = 3+3*mjs; tm0 = mjs; tm1 = mjs; sgn = 1.0; }
      else { int mjs = s-5; col = 15+3*mjs; tm0 = mi; tm1 = mjs; sgn = -1.0; }
      double S1=0,S2v=0,S3=0;
      for (int u=0;u<16;++u){
        S1 += red2[u*27+col]; S2v += red2[u*27+col+1]; S3 += red2[u*27+col+2];
      }
      double cS = sgn*gsc;
      double exx = cS*(S1*h0d*h0d);
      double exy = cS*(S1*h0d*h1d);
      double exz = cS*(S1*h0d*h2d + S2v*h0d);
      double eyy = cS*(S1*h1d*h1d);
      double eyz = cS*(S1*h1d*h2d + S2v*h1d);
      double ezz = cS*(S1*h2d*h2d + 2.0*S2v*h2d + S3);
      double* M = Mg + cp*96 + (tm0*4+tm1)*6;
      atomicAdd(&M[0], exx); atomicAdd(&M[1], exy); atomicAdd(&M[2], exz);
      atomicAdd(&M[3], eyy); atomicAdd(&M[4], eyz); atomicAdd(&M[5], ezz);
    }
  } else if (b < KS_B + REG_B) {
    // =============== real-space gradient + energy ==========================
    int r = b - KS_B; int nn = r >> 4, ic = r & 15;
    int cp = (nn + 2*ic) & (NCPY-1);
    double* g = gN + cp*768;
    double n0 = (double)(nn/5 - 2), n1 = (double)(nn%5 - 2);
    float a0 = (float)(n0*(double)cell[0] + n1*(double)cell[3]);
    float a1c = (float)(n0*(double)cell[1] + n1*(double)cell[4]);
    float a2c = (float)(n0*(double)cell[2] + n1*(double)cell[5]);
    float *px=f, *py=f+256, *pz=f+512, *pq=f+768;
    double* redg = shd + 896;
    {
      int a = tid;
      float4 p = posf4[a];
      px[a]=p.x; py[a]=p.y; pz[a]=p.z; pq[a]=p.w;
    }
    __syncthreads();
    int il = tid >> 4, jl = tid & 15;
    int i = ic*16 + il;
    float xi=px[i], yi=py[i], zi=pz[i], qi=pq[i];
    double gx=0,gy=0,gz=0,Rp=0;
    #pragma unroll
    for (int tq=0;tq<4;++tq){
      float fgx=0.f, fgy=0.f, fgz=0.f, fRp=0.f;
      #pragma unroll
      for (int ts=0;ts<4;++ts){
        int j = (tq*4+ts)*16 + jl;
        float rx = xi - px[j] + a0;
        float ry = yi - py[j] + a1c;
        float rz = zi - pz[j] + a2c;
        float dsq = rx*rx+ry*ry+rz*rz;
        if (dsq > 0.0f){
          float d = sqrtf(dsq);
          float invd = __fdividef(1.0f, d);
          float ad = AL_F*d;
          float ec = fast_erfcf(ad);
          float ex = __expf(-ad*ad);
          float qq = qi*pq[j];
          float P  = -(K1_F*ex*invd + ec*invd*invd);
          float C  = qq*P*invd;
          fRp = fmaf(qq, ec*invd, fRp);
          fgx = fmaf(C, rx, fgx); fgy = fmaf(C, ry, fgy); fgz = fmaf(C, rz, fgz);
        }
      }
      gx += (double)fgx; gy += (double)fgy; gz += (double)fgz; Rp += (double)fRp;
    }
    #pragma unroll
    for (int m=1;m<16;m<<=1){
      gx += __shfl_xor(gx, m); gy += __shfl_xor(gy, m); gz += __shfl_xor(gz, m);
      Rp += __shfl_xor(Rp, m);
    }
    if (jl == 0){
      atomicAdd(&g[i*3+0], 4.0*KE_C*gx);
      atomicAdd(&g[i*3+1], 4.0*KE_C*gy);
      atomicAdd(&g[i*3+2], 4.0*KE_C*gz);
      redg[il] = Rp;
    }
    __syncthreads();
    if (tid == 0){
      double s = 0.0;
      #pragma unroll
      for (int u=0;u<16;++u) s += redg[u];
      atomicAdd(&scal[cp*8+2], s);
    }
  } else if (b < KS_B + REG_B + REM_B) {
    // =============== real-space Hessian M: (cell, mi, mj) blocks ===========
    int rb = b - (KS_B + REG_B);
    int nn = rb >> 4, mp = rb & 15;
    int mi = mp >> 2, mjm = mp & 3;
    int cp = (nn + mp) & (NCPY-1);
    double n0 = (double)(nn/5 - 2), n1 = (double)(nn%5 - 2);
    float a0 = (float)(n0*(double)cell[0] + n1*(double)cell[3]);
    float a1c = (float)(n0*(double)cell[1] + n1*(double)cell[4]);
    float a2c = (float)(n0*(double)cell[2] + n1*(double)cell[5]);
    float *px=f, *py=f+256, *pz=f+512, *pq=f+768, *pm=f+1024; // 640 dbl
    double* red2m = shd + 640;   // 64 x 21 = 1344 dbl -> ends 1984
    double* redS  = shd + 1984;  // 21 dbl
    {
      int a = tid;
      float4 p = posf4[a];
      px[a]=p.x; py[a]=p.y; pz[a]=p.z; pq[a]=p.w;
      pm[a] = film[a] > 0 ? 1.0f : 0.0f;
    }
    __syncthreads();
    int il = tid >> 2, jl = tid & 3;
    int i = mi*64 + il;
    float xi=px[i], yi=py[i], zi=pz[i], qi=pq[i];
    double msi = (double)pm[i];
    double u0=0,u1v=0,u2v=0,u3=0,u4=0,u5=0,u6=0;
    double m0=0,m1v=0,m2v=0,m3=0,m4=0,m5=0,m6=0;
    #pragma unroll
    for (int tq=0;tq<4;++tq){
      float c0=0.f,c1=0.f,c2=0.f,c3=0.f,c4=0.f,c5=0.f,c6=0.f;
      float d0=0.f,d1=0.f,d2=0.f,d3=0.f,d4=0.f,d5=0.f,d6=0.f;
      #pragma unroll
      for (int ts=0;ts<4;++ts){
        int jg = mjm*64 + (tq*4+ts)*4 + jl;
        float rx = xi - px[jg] + a0;
        float ry = yi - py[jg] + a1c;
        float rz = zi - pz[jg] + a2c;
        float dsq = rx*rx+ry*ry+rz*rz;
        if (dsq > 0.0f && jg != i){
          float d = sqrtf(dsq);
          float invd = __fdividef(1.0f, d);
          float invd2 = invd*invd;
          float ad = AL_F*d;
          float ec = fast_erfcf(ad);
          float ex = __expf(-ad*ad);
          float qq = qi*pq[jg];
          float P  = -(K1_F*ex*invd + ec*invd2);
          float b1 = qq*P*invd;
          float bW = qq*invd*( K1_F*ex*(TWOA2_F + 3.0f*invd2)*invd + 3.0f*ec*invd2*invd2 );
          float w1=bW*rx*rx, w2=bW*rx*ry, w3=bW*rx*rz, w4=bW*ry*ry, w5=bW*ry*rz, w6=bW*rz*rz;
          c0+=b1; c1+=w1; c2+=w2; c3+=w3; c4+=w4; c5+=w5; c6+=w6;
          float mj_ = pm[jg];
          d0=fmaf(b1,mj_,d0); d1=fmaf(w1,mj_,d1); d2=fmaf(w2,mj_,d2);
          d3=fmaf(w3,mj_,d3); d4=fmaf(w4,mj_,d4); d5=fmaf(w5,mj_,d5); d6=fmaf(w6,mj_,d6);
        }
      }
      u0+=(double)c0; u1v+=(double)c1; u2v+=(double)c2; u3+=(double)c3;
      u4+=(double)c4; u5+=(double)c5; u6+=(double)c6;
      m0+=(double)d0; m1v+=(double)d1; m2v+=(double)d2; m3+=(double)d3;
      m4+=(double)d4; m5+=(double)d5; m6+=(double)d6;
    }
    #pragma unroll
    for (int m=1;m<4;m<<=1){
      u0+=__shfl_xor(u0,m); u1v+=__shfl_xor(u1v,m); u2v+=__shfl_xor(u2v,m);
      u3+=__shfl_xor(u3,m); u4+=__shfl_xor(u4,m); u5+=__shfl_xor(u5,m); u6+=__shfl_xor(u6,m);
      m0+=__shfl_xor(m0,m); m1v+=__shfl_xor(m1v,m); m2v+=__shfl_xor(m2v,m);
      m3+=__shfl_xor(m3,m); m4+=__shfl_xor(m4,m); m5+=__shfl_xor(m5,m); m6+=__shfl_xor(m6,m);
    }
    if (jl == 0){
      double* rr = red2m + il*21;
      rr[0]=msi*u0; rr[1]=msi*u1v; rr[2]=msi*u2v; rr[3]=msi*u3;
      rr[4]=msi*u4; rr[5]=msi*u5; rr[6]=msi*u6;
      rr[7]=m0; rr[8]=m1v; rr[9]=m2v; rr[10]=m3; rr[11]=m4; rr[12]=m5; rr[13]=m6;
      rr[14]=msi*m0; rr[15]=msi*m1v; rr[16]=msi*m2v; rr[17]=msi*m3;
      rr[18]=msi*m4; rr[19]=msi*m5; rr[20]=msi*m6;
    }
    __syncthreads();
    if (tid < 21){
      double s = 0.0;
      for (int u=0;u<64;++u) s += red2m[u*21+tid];
      redS[tid] = s;
    }
    __syncthreads();
    if (tid < 18){
      int slot = tid/6, e = tid%6;
      const double* S = redS + slot*7;
      double val;
      if (e==0) val = S[0] + S[1];
      else if (e==1) val = S[2];
      else if (e==2) val = S[3];
      else if (e==3) val = S[0] + S[4];
      else if (e==4) val = S[5];
      else val = S[0] + S[6];
      double sgn = (slot==2) ? -1.0 : 1.0;
      int tm0 = (slot==1) ? mjm : mi;
      int tm1 = (slot==0) ? mi : mjm;
      atomicAdd(&Mg[cp*96 + (tm0*4+tm1)*6 + e], sgn*2.0*KE_C*val);
    }
  } else if (b < KS_B + REG_B + REM_B + BO_B) {
    // =============== Born: gradient + energy + M ===========================
    int bb = b - (KS_B + REG_B + REM_B);
    int cp = bb & (NCPY-1);
    double* g = gN + cp*768;
    int p = bb*256 + tid;
    int ai = ii[p], aj = jj[p];
    double rx = posc(R,shiftv,im,film,aj,0) - posc(R,shiftv,im,film,ai,0) + (double)offs[p*3+0];
    double ry = posc(R,shiftv,im,film,aj,1) - posc(R,shiftv,im,film,ai,1) + (double)offs[p*3+1];
    double rz = posc(R,shiftv,im,film,aj,2) - posc(R,shiftv,im,film,ai,2) + (double)offs[p*3+2];
    double dsq = rx*rx + ry*ry + rz*rz;
    double d = sqrt(dsq);
    double y = 0.0;
    if (d < CUTOFF_C) {
      double qq = fabs((double)q[ai]*(double)q[aj]);
      int    ni = (int)(na[p] + 0.5f);
      double n  = (double)ni;
      double B  = qq * ipown((double)r0a[p], ni-1) / n;
      double dmn = ipown(1.0/d, ni);
      y = 0.5*KE_C*B*(dmn - ipown(1.0/CUTOFF_C, ni));
      double c = (-0.5*KE_C*n*B) * (dmn / dsq);
      atomicAdd(&g[aj*3+0],  c*rx);
      atomicAdd(&g[aj*3+1],  c*ry);
      atomicAdd(&g[aj*3+2],  c*rz);
      atomicAdd(&g[ai*3+0], -c*rx);
      atomicAdd(&g[ai*3+1], -c*ry);
      atomicAdd(&g[ai*3+2], -c*rz);
      // Hessian M
      bool fi = film[ai] > 0, fj = film[aj] > 0;
      if (fi || fj){
        double b2 = -c*(n+2.0)/dsq;
        double E0 = c + b2*rx*rx, E1 = b2*rx*ry, E2 = b2*rx*rz;
        double E3 = c + b2*ry*ry, E4 = b2*ry*rz, E5 = c + b2*rz*rz;
        double* M = Mg + cp*96;
        int mi_ = im[ai], mj_ = im[aj];
        if (fi){
          double* t = M + (mi_*4+mi_)*6;
          atomicAdd(&t[0],E0); atomicAdd(&t[1],E1); atomicAdd(&t[2],E2);
          atomicAdd(&t[3],E3); atomicAdd(&t[4],E4); atomicAdd(&t[5],E5);
        }
        if (fj){
          double* t = M + (mj_*4+mj_)*6;
          atomicAdd(&t[0],E0); atomicAdd(&t[1],E1); atomicAdd(&t[2],E2);
          atomicAdd(&t[3],E3); atomicAdd(&t[4],E4); atomicAdd(&t[5],E5);
        }
        if (fi && fj){
          if (mi_ != mj_){
            double* t = M + (mi_*4+mj_)*6;
            atomicAdd(&t[0],-E0); atomicAdd(&t[1],-E1); atomicAdd(&t[2],-E2);
            atomicAdd(&t[3],-E3); atomicAdd(&t[4],-E4); atomicAdd(&t[5],-E5);
            double* u = M + (mj_*4+mi_)*6;
            atomicAdd(&u[0],-E0); atomicAdd(&u[1],-E1); atomicAdd(&u[2],-E2);
            atomicAdd(&u[3],-E3); atomicAdd(&u[4],-E4); atomicAdd(&u[5],-E5);
          } else {
            double* t = M + (mi_*4+mi_)*6;
            atomicAdd(&t[0],-2.0*E0); atomicAdd(&t[1],-2.0*E1); atomicAdd(&t[2],-2.0*E2);
            atomicAdd(&t[3],-2.0*E3); atomicAdd(&t[4],-2.0*E4); atomicAdd(&t[5],-2.0*E5);
          }
        }
      }
    }
    {
      int myMol = im[ai];
      #pragma unroll
      for (int mm=0; mm<4; ++mm){
        double v = (myMol==mm) ? y : 0.0;
        for (int off=32; off; off>>=1) v += __shfl_down(v, off, 64);
        if ((tid & 63) == 0 && v != 0.0)
          atomicAdd(&scal[cp*8+3+mm], v);
      }
    }
  } else {
    // =============== S2: gradient + energy + M (zz only) ===================
    int jc = b - (KS_B + REG_B + REM_B + BO_B);
    int cp = (jc*2+1) & (NCPY-1);
    double* g = gN + cp*768;
    float *zz=f, *zq=f+32, *zm=f+64;
    if (tid < 32) {
      int j = jc*32 + tid;
      float4 p = posf4[j];
      zz[tid] = p.z; zq[tid] = p.w;
      zm[tid] = film[j] > 0 ? 1.0f : 0.0f;
    }
    __syncthreads();
    float4 pi = posf4[tid];
    float ziv = pi.z, qi = pi.w;
    double msi = film[tid] > 0 ? 1.0 : 0.0;
    int mi = tid >> 6, mjs2 = jc >> 1;
    double acc = 0.0, S2p = 0.0;
    double uii=0.0, ujj=0.0, uij=0.0;
    for (int j2=0;j2<32;++j2){
      int jg = jc*32 + j2;
      float z = ziv - zz[j2];
      float az = AL_F*z;
      float qq = qi*zq[j2];
      float ex = __expf(-az*az);
      float e = 1.0f - fast_erfcf(az);
      S2p += (double)(qq*(z*e + ex*IAS_F));
      acc += (double)(qq*e);
      if (jg != tid){
        double gpp = (double)(qq*K1_F*ex);
        double mj_ = (double)zm[j2];
        uii += msi*gpp;
        ujj += mj_*gpp;
        uij += msi*mj_*gpp;
      }
    }
    double area = cell_area(cell);
    atomicAdd(&g[tid*3+2], (-8.0*KE_C*PI_D/area)*acc);
    #pragma unroll
    for (int m=1;m<64;m<<=1){
      S2p += __shfl_xor(S2p, m);
      uii += __shfl_xor(uii, m); ujj += __shfl_xor(ujj, m); uij += __shfl_xor(uij, m);
    }
    if ((tid & 63) == 0){
      atomicAdd(&scal[cp*8+1], S2p);
      double Cs = -4.0*KE_C*PI_D/area;
      atomicAdd(&Mg[cp*96 + (mi*4+mi)*6 + 5],     Cs*uii);
      atomicAdd(&Mg[cp*96 + (mjs2*4+mjs2)*6 + 5], Cs*ujj);
      atomicAdd(&Mg[cp*96 + (mi*4+mjs2)*6 + 5],  -Cs*uij);
    }
  }
}

// ---------------- finish: energies, ffn, fng = -2 M ff ----------------------
__global__ void finish_kernel(const double* gN, const double* scal, const double* Mg,
                              const float* q, const float* cell, const int* im,
                              const int* film, float* out){
  __shared__ double shd[1024];
  double* gsh  = shd;        // 768
  double* ffsh = shd + 768;  // 12
  double* Msh  = shd + 800;  // 96
  int i = threadIdx.x;
  double s0=0,s1=0,s2v=0;
  for (int c=0;c<NCPY;++c){
    const double* g = gN + c*768;
    s0 += g[i*3+0]; s1 += g[i*3+1]; s2v += g[i*3+2];
  }
  gsh[i*3+0]=s0; gsh[i*3+1]=s1; gsh[i*3+2]=s2v;
  if (i < 96){
    double s = 0.0;
    for (int c=0;c<NCPY;++c) s += Mg[c*96 + i];
    Msh[i] = s;
  }
  __syncthreads();
  if (i < 12) {
    int mm = i/3, c = i%3;
    double s = 0.0;
    for (int a = 0; a < N_ATOMS; ++a)
      if (im[a] == mm && film[a] > 0) s -= gsh[a*3+c];
    ffsh[i] = s;
  }
  __syncthreads();
  if (i == 0) {
    double qs = 0.0;
    for (int a = 0; a < N_ATOMS; ++a){ double qa=(double)q[a]; qs += qa*qa; }
    double area = cell_area(cell);
    double S=0,S2=0,RR=0,bm[4]={0,0,0,0};
    for (int c=0;c<NCPY;++c){
      S += scal[c*8+0]; S2 += scal[c*8+1]; RR += scal[c*8+2];
      for (int m=0;m<4;++m) bm[m] += scal[c*8+3+m];
    }
    double recip = KE_C*PI_D*(S/(2.0*area) - S2/area);
    double realE = 0.5*KE_C*RR;
    double selfE = -ALPHA_C/sqrt(PI_D)*qs*KE_C;
    double Ec = recip + realE + selfE;
    out[4] = (float)Ec;
    for (int m = 0; m < 4; ++m) {
      out[5+m] = (float)bm[m];
      out[m]   = (float)(Ec + bm[m]);
    }
  }
  if (i < 4) {
    double f0 = ffsh[i*3+0], f1 = ffsh[i*3+1], f2 = ffsh[i*3+2];
    out[9+i] = (float)(f0*f0 + f1*f1 + f2*f2);
  }
  if (i < 12) {
    int m = i/3, c = i%3;
    const int sidx[3][3] = {{0,1,2},{1,3,4},{2,4,5}};
    double s = 0.0;
    for (int m2=0;m2<4;++m2)
      for (int c2=0;c2<3;++c2)
        s += Msh[(m*4+m2)*6 + sidx[c][c2]] * ffsh[m2*3+c2];
    out[13+i] = (float)(-2.0*s);
  }
}

extern "C" void kernel_launch(void* const* d_in, const int* in_sizes, int n_in,
                              void* d_out, int out_size, void* d_ws, size_t ws_size,
                              hipStream_t stream){
  const float* R      = (const float*)d_in[0];
  const float* shiftv = (const float*)d_in[1];
  const float* q      = (const float*)d_in[2];
  const float* offs   = (const float*)d_in[3];
  const float* cell   = (const float*)d_in[4];
  const float* recipc = (const float*)d_in[5];
  const float* r0a    = (const float*)d_in[6];
  const float* na     = (const float*)d_in[7];
  const int*   ii     = (const int*)d_in[8];
  const int*   jj     = (const int*)d_in[9];
  const int*   im     = (const int*)d_in[10];
  const int*   film   = (const int*)d_in[11];
  float* out = (float*)d_out;

  double* ws   = (double*)d_ws;
  double* scal = ws;                         // NCPY*8   = 128
  double* gN   = ws + NCPY*8;                // NCPY*768 = 12288
  double* Mg   = ws + NCPY*8 + NCPY*768;     // NCPY*96  = 1536
  float4* tab4  = (float4*)(ws + ZWORDS);    // 84*256 float4
  float4* posf4 = tab4 + 84*256;             // 256 float4

  hipLaunchKernelGGL(prep_kernel, dim3(NPREP), dim3(256), 0, stream,
                     R, shiftv, q, im, film, recipc, ws, tab4, posf4);
  hipLaunchKernelGGL(pass_kernel, dim3(NBLK), dim3(256), 0, stream,
                     R, shiftv, q, offs, cell, recipc, r0a, na, ii, jj, im, film,
                     tab4, posf4, gN, scal, Mg);
  hipLaunchKernelGGL(finish_kernel, dim3(1), dim3(256), 0, stream,
                     gN, scal, Mg, q, cell, im, film, out);
}

// Round 13
// 129.832 us; speedup vs baseline: 3.3980x; 1.0899x over previous
//
#include <hip/hip_runtime.h>

#define N_ATOMS 256
#define N_MOL 4
#define N_PAIRS 8192
#define KE_C 14.3996
#define ALPHA_C 0.3
#define CUTOFF_C 6.0

#define KS_B 1344   // 84 k x 16 i-chunks
#define REG_B 400   // 25 cells x 16 i-chunks (gradient)
#define REM_B 400   // 25 cells x 16 mol-pairs (Hessian M)
#define BO_B 32
#define S2_B 8
#define NBLK (KS_B+REG_B+REM_B+BO_B+S2_B)
#define NCPY 16
#define NPREP 85
#define ZWORDS (NCPY*8 + NCPY*768 + NCPY*96)   // scal + gN + Mg = 13952 doubles

constexpr double PI_D = 3.14159265358979323846;
#define AL_F 0.3f
#define TWOSQPI_F 1.12837917f
#define K1_F 0.33851375f    // TWOSQPI*ALPHA
#define IAS_F 1.8806320f    // 1/(ALPHA*sqrt(pi))
#define TWOA2_F 0.18f       // 2*ALPHA^2

__device__ __forceinline__ float fast_erfcf(float x){
  float ax = fabsf(x);
  float t = __fdividef(1.0f, fmaf(0.5f, ax, 1.0f));
  float p = 0.17087277f;
  p = fmaf(p, t, -0.82215223f);
  p = fmaf(p, t,  1.48851587f);
  p = fmaf(p, t, -1.13520398f);
  p = fmaf(p, t,  0.27886807f);
  p = fmaf(p, t, -0.18628806f);
  p = fmaf(p, t,  0.09678418f);
  p = fmaf(p, t,  0.37409196f);
  p = fmaf(p, t,  1.00002368f);
  p = fmaf(p, t, -1.26551223f);
  float ans = t*__expf(fmaf(-ax, ax, p));
  return x >= 0.0f ? ans : 2.0f - ans;
}

__device__ inline double ipown(double x, int e){
  double r = 1.0;
  while (e){ if (e & 1) r *= x; x *= x; e >>= 1; }
  return r;
}

__device__ inline double cell_area(const float* cell){
  double a0=cell[0], a1=cell[1], a2=cell[2];
  double b0=cell[3], b1=cell[4], b2=cell[5];
  double cx=a1*b2-a2*b1, cy=a2*b0-a0*b2, cz=a0*b1-a1*b0;
  return sqrt(cx*cx+cy*cy+cz*cz);
}
__device__ inline double posc(const float* R, const float* shiftv, const int* im,
                              const int* film, int a, int c){
  double mask = film[a] > 0 ? 1.0 : 0.0;
  return (double)R[a*3+c] + mask*(double)shiftv[im[a]*3+c];
}

// ---------------- prep: zero accumulators; build k-table + pos table --------
__global__ __launch_bounds__(256) void prep_kernel(
    const float* R, const float* shiftv, const float* q, const int* im,
    const int* film, const float* recipc, double* ws, float4* tab4, float4* posf4){
  int b = blockIdx.x, tid = threadIdx.x;
  { int w = b*256 + tid; if (w < ZWORDS) ws[w] = 0.0; }
  int a = tid;
  double xa = posc(R,shiftv,im,film,a,0);
  double ya = posc(R,shiftv,im,film,a,1);
  double za = posc(R,shiftv,im,film,a,2);
  if (b < 84) {
    double b0 = (double)(b/13 - 6), b1 = (double)(b%13 - 6);
    double TP = 2.0*PI_D;
    double h0 = TP*(b0*(double)recipc[0] + b1*(double)recipc[3]);
    double h1 = TP*(b0*(double)recipc[1] + b1*(double)recipc[4]);
    double h2 = TP*(b0*(double)recipc[2] + b1*(double)recipc[5]);
    double kap = sqrt(h0*h0 + h1*h1 + h2*h2);
    double phi = h0*xa + h1*ya + h2*za;
    double s, c; sincos(phi, &s, &c);
    double E = exp(kap*za);
    tab4[b*256+a] = make_float4((float)c, (float)s, (float)E, (float)(1.0/E));
  } else if (b == 84) {
    posf4[a] = make_float4((float)xa, (float)ya, (float)za, q[a]);
  }
}

// ---------------- single pass: gradient + energies + 12x12 Hessian M --------
__global__ __launch_bounds__(256) void pass_kernel(
    const float* R, const float* shiftv, const float* q, const float* offs,
    const float* cell, const float* recipc, const float* r0a, const float* na,
    const int* ii, const int* jj, const int* im, const int* film,
    const float4* tab4, const float4* posf4,
    double* gN, double* scal, double* Mg){
  __shared__ __align__(16) double shd[2048];   // 16 KB aliased
  float* f = (float*)shd;
  int b = blockIdx.x, tid = threadIdx.x;

  if (b < KS_B) {
    // =============== k-space: kk = b>>4, i-chunk ic = b&15 =================
    int kk = b >> 4, ic = b & 15;
    int mi = ic >> 2;
    int cp = (kk + 2*ic) & (NCPY-1);
    double* g = gN + cp*768;
    double b0 = (double)(kk/13 - 6), b1d = (double)(kk%13 - 6);
    double TP = 2.0*PI_D;
    double h0d = TP*(b0*(double)recipc[0] + b1d*(double)recipc[3]);
    double h1d = TP*(b0*(double)recipc[1] + b1d*(double)recipc[4]);
    double h2d = TP*(b0*(double)recipc[2] + b1d*(double)recipc[5]);
    double kapd = sqrt(h0d*h0d + h1d*h1d + h2d*h2d);
    float A    = (float)(kapd/(2.0*ALPHA_C));
    float ikap = (float)(1.0/kapd);
    float kapf = (float)kapd;
    float EA   = __expf(-A*A);
    float4* t4 = (float4*)f;          // f[0..1023]
    float* pzs = f + 1024;
    float* pqs = f + 1280;
    float* pms = f + 1536;            // ends f[1792) = shd dbl 896
    double* red2  = shd + 896;        // 16 x 27 = 432 dbl
    double* redsp = shd + 1344;       // 16 dbl
    {
      int a = tid;
      t4[a] = tab4[kk*256 + a];
      float4 p = posf4[a];
      pzs[a] = p.z; pqs[a] = p.w;
      pms[a] = film[a] > 0 ? 1.0f : 0.0f;
    }
    __syncthreads();
    int il = tid >> 4, jl = tid & 15;
    int i = ic*16 + il;
    float4 ti = t4[i];
    float ci=ti.x, si=ti.y, Ei=ti.z, iEi=ti.w;
    float zi=pzs[i], qi=pqs[i];
    double Sp=0.0, cmS=0.0, czS=0.0;
    double Aall0=0,Aall1=0,Aall2=0;
    double AmA0=0,AmA1=0,AmA2=0, AmB0=0,AmB1=0,AmB2=0;
    double AmC0=0,AmC1=0,AmC2=0, AmD0=0,AmD1=0,AmD2=0;
    #pragma unroll
    for (int tq=0; tq<4; ++tq){
      // fp32 chunk accumulators (promoted to fp64 once per 4-iter chunk)
      float fSp=0.f, fcm=0.f, fcz=0.f;
      float fA0=0.f, fA1=0.f, fA2=0.f;
      float fg0=0.f, fg1=0.f, fg2=0.f;
      #pragma unroll
      for (int ts=0; ts<4; ++ts){
        int t = tq*4+ts;
        int jg = t*16 + jl;
        float4 tj = t4[jg];
        float z  = zi - pzs[jg];
        float az = AL_F*z;
        float u1 = A + az, u2 = A - az;
        float ec1 = fast_erfcf(u1), ec2 = fast_erfcf(u2);
        float ekz = Ei*tj.w, ikz = iEi*tj.z;
        float e1 = ekz*ec1, e2 = ikz*ec2;
        float cph = ci*tj.x + si*tj.y;
        float sph = si*tj.x - ci*tj.y;
        float em  = e1 - e2;
        float fF  = (e1+e2)*ikap;
        float pcf = cph*fF;
        float qq  = qi*pqs[jg];
        fSp = fmaf(qq, pcf, fSp);
        fcm = fmaf(-2.0f*qq, sph*fF, fcm);
        fcz = fmaf( 2.0f*qq, cph*em, fcz);
        // Hessian scalars (skip self-term j==i)
        float mm = (jg != i) ? 1.0f : 0.0f;
        float Gs = TWOSQPI_F*EA*__expf(-az*az);
        float F2 = kapf*(e1+e2) - 2.0f*AL_F*Gs;
        float a1 = -qq*pcf*mm;
        float a2 = -qq*sph*em*mm;
        float a3 =  qq*cph*F2*mm;
        fA0 += a1; fA1 += a2; fA2 += a3;
        float mj_ = pms[jg];
        fg0 = fmaf(a1, mj_, fg0); fg1 = fmaf(a2, mj_, fg1); fg2 = fmaf(a3, mj_, fg2);
      }
      Sp += (double)fSp; cmS += (double)fcm; czS += (double)fcz;
      Aall0 += (double)fA0; Aall1 += (double)fA1; Aall2 += (double)fA2;
      if      (tq==0){ AmA0=(double)fg0; AmA1=(double)fg1; AmA2=(double)fg2; }
      else if (tq==1){ AmB0=(double)fg0; AmB1=(double)fg1; AmB2=(double)fg2; }
      else if (tq==2){ AmC0=(double)fg0; AmC1=(double)fg1; AmC2=(double)fg2; }
      else           { AmD0=(double)fg0; AmD1=(double)fg1; AmD2=(double)fg2; }
    }
    #pragma unroll
    for (int m=1;m<16;m<<=1){
      Sp += __shfl_xor(Sp, m); cmS += __shfl_xor(cmS, m); czS += __shfl_xor(czS, m);
      Aall0+=__shfl_xor(Aall0,m); Aall1+=__shfl_xor(Aall1,m); Aall2+=__shfl_xor(Aall2,m);
      AmA0+=__shfl_xor(AmA0,m); AmA1+=__shfl_xor(AmA1,m); AmA2+=__shfl_xor(AmA2,m);
      AmB0+=__shfl_xor(AmB0,m); AmB1+=__shfl_xor(AmB1,m); AmB2+=__shfl_xor(AmB2,m);
      AmC0+=__shfl_xor(AmC0,m); AmC1+=__shfl_xor(AmC1,m); AmC2+=__shfl_xor(AmC2,m);
      AmD0+=__shfl_xor(AmD0,m); AmD1+=__shfl_xor(AmD1,m); AmD2+=__shfl_xor(AmD2,m);
    }
    double gsc = 4.0*KE_C*PI_D/cell_area(cell);
    if (jl == 0){
      atomicAdd(&g[i*3+0], gsc*(h0d*cmS));
      atomicAdd(&g[i*3+1], gsc*(h1d*cmS));
      atomicAdd(&g[i*3+2], gsc*(h2d*cmS + czS));
      redsp[il] = Sp;
      double msi = (double)pms[i];
      double* r = red2 + il*27;
      r[0]=msi*Aall0; r[1]=msi*Aall1; r[2]=msi*Aall2;
      r[3]=AmA0; r[4]=AmA1; r[5]=AmA2;
      r[6]=AmB0; r[7]=AmB1; r[8]=AmB2;
      r[9]=AmC0; r[10]=AmC1; r[11]=AmC2;
      r[12]=AmD0; r[13]=AmD1; r[14]=AmD2;
      r[15]=msi*AmA0; r[16]=msi*AmA1; r[17]=msi*AmA2;
      r[18]=msi*AmB0; r[19]=msi*AmB1; r[20]=msi*AmB2;
      r[21]=msi*AmC0; r[22]=msi*AmC1; r[23]=msi*AmC2;
      r[24]=msi*AmD0; r[25]=msi*AmD1; r[26]=msi*AmD2;
    }
    __syncthreads();
    if (tid == 0){
      double s = 0.0;
      #pragma unroll
      for (int u=0;u<16;++u) s += redsp[u];
      atomicAdd(&scal[cp*8+0], 2.0*s);
    }
    if (tid < 9){
      int s = tid;
      int col, tm0, tm1; double sgn;
      if (s == 0){ col = 0; tm0 = mi; tm1 = mi; sgn = 1.0; }
      else if (s < 5){ int mjs = s-1; col = 3+3*mjs; tm0 = mjs; tm1 = mjs; sgn = 1.0; }
      else { int mjs = s-5; col = 15+3*mjs; tm0 = mi; tm1 = mjs; sgn = -1.0; }
      double S1=0,S2v=0,S3=0;
      for (int u=0;u<16;++u){
        S1 += red2[u*27+col]; S2v += red2[u*27+col+1]; S3 += red2[u*27+col+2];
      }
      double cS = sgn*gsc;
      double exx = cS*(S1*h0d*h0d);
      double exy = cS*(S1*h0d*h1d);
      double exz = cS*(S1*h0d*h2d + S2v*h0d);
      double eyy = cS*(S1*h1d*h1d);
      double eyz = cS*(S1*h1d*h2d + S2v*h1d);
      double ezz = cS*(S1*h2d*h2d + 2.0*S2v*h2d + S3);
      double* M = Mg + cp*96 + (tm0*4+tm1)*6;
      atomicAdd(&M[0], exx); atomicAdd(&M[1], exy); atomicAdd(&M[2], exz);
      atomicAdd(&M[3], eyy); atomicAdd(&M[4], eyz); atomicAdd(&M[5], ezz);
    }
  } else if (b < KS_B + REG_B) {
    // =============== real-space gradient + energy ==========================
    int r = b - KS_B; int nn = r >> 4, ic = r & 15;
    int cp = (nn + 2*ic) & (NCPY-1);
    double* g = gN + cp*768;
    double n0 = (double)(nn/5 - 2), n1 = (double)(nn%5 - 2);
    float a0 = (float)(n0*(double)cell[0] + n1*(double)cell[3]);
    float a1c = (float)(n0*(double)cell[1] + n1*(double)cell[4]);
    float a2c = (float)(n0*(double)cell[2] + n1*(double)cell[5]);
    float *px=f, *py=f+256, *pz=f+512, *pq=f+768;
    double* redg = shd + 896;
    {
      int a = tid;
      float4 p = posf4[a];
      px[a]=p.x; py[a]=p.y; pz[a]=p.z; pq[a]=p.w;
    }
    __syncthreads();
    int il = tid >> 4, jl = tid & 15;
    int i = ic*16 + il;
    float xi=px[i], yi=py[i], zi=pz[i], qi=pq[i];
    double gx=0,gy=0,gz=0,Rp=0;
    #pragma unroll
    for (int tq=0;tq<4;++tq){
      float fgx=0.f, fgy=0.f, fgz=0.f, fRp=0.f;
      #pragma unroll
      for (int ts=0;ts<4;++ts){
        int j = (tq*4+ts)*16 + jl;
        float rx = xi - px[j] + a0;
        float ry = yi - py[j] + a1c;
        float rz = zi - pz[j] + a2c;
        float dsq = rx*rx+ry*ry+rz*rz;
        if (dsq > 0.0f){
          float d = sqrtf(dsq);
          float invd = __fdividef(1.0f, d);
          float ad = AL_F*d;
          float ec = fast_erfcf(ad);
          float ex = __expf(-ad*ad);
          float qq = qi*pq[j];
          float P  = -(K1_F*ex*invd + ec*invd*invd);
          float C  = qq*P*invd;
          fRp = fmaf(qq, ec*invd, fRp);
          fgx = fmaf(C, rx, fgx); fgy = fmaf(C, ry, fgy); fgz = fmaf(C, rz, fgz);
        }
      }
      gx += (double)fgx; gy += (double)fgy; gz += (double)fgz; Rp += (double)fRp;
    }
    #pragma unroll
    for (int m=1;m<16;m<<=1){
      gx += __shfl_xor(gx, m); gy += __shfl_xor(gy, m); gz += __shfl_xor(gz, m);
      Rp += __shfl_xor(Rp, m);
    }
    if (jl == 0){
      atomicAdd(&g[i*3+0], 4.0*KE_C*gx);
      atomicAdd(&g[i*3+1], 4.0*KE_C*gy);
      atomicAdd(&g[i*3+2], 4.0*KE_C*gz);
      redg[il] = Rp;
    }
    __syncthreads();
    if (tid == 0){
      double s = 0.0;
      #pragma unroll
      for (int u=0;u<16;++u) s += redg[u];
      atomicAdd(&scal[cp*8+2], s);
    }
  } else if (b < KS_B + REG_B + REM_B) {
    // =============== real-space Hessian M: (cell, mi, mj) blocks ===========
    int rb = b - (KS_B + REG_B);
    int nn = rb >> 4, mp = rb & 15;
    int mi = mp >> 2, mjm = mp & 3;
    int cp = (nn + mp) & (NCPY-1);
    double n0 = (double)(nn/5 - 2), n1 = (double)(nn%5 - 2);
    float a0 = (float)(n0*(double)cell[0] + n1*(double)cell[3]);
    float a1c = (float)(n0*(double)cell[1] + n1*(double)cell[4]);
    float a2c = (float)(n0*(double)cell[2] + n1*(double)cell[5]);
    float *px=f, *py=f+256, *pz=f+512, *pq=f+768, *pm=f+1024; // 640 dbl
    double* red2m = shd + 640;   // 64 x 21 = 1344 dbl -> ends 1984
    double* redS  = shd + 1984;  // 21 dbl
    {
      int a = tid;
      float4 p = posf4[a];
      px[a]=p.x; py[a]=p.y; pz[a]=p.z; pq[a]=p.w;
      pm[a] = film[a] > 0 ? 1.0f : 0.0f;
    }
    __syncthreads();
    int il = tid >> 2, jl = tid & 3;
    int i = mi*64 + il;
    float xi=px[i], yi=py[i], zi=pz[i], qi=pq[i];
    double msi = (double)pm[i];
    double u0=0,u1v=0,u2v=0,u3=0,u4=0,u5=0,u6=0;
    double m0=0,m1v=0,m2v=0,m3=0,m4=0,m5=0,m6=0;
    #pragma unroll
    for (int tq=0;tq<4;++tq){
      float c0=0.f,c1=0.f,c2=0.f,c3=0.f,c4=0.f,c5=0.f,c6=0.f;
      float d0=0.f,d1=0.f,d2=0.f,d3=0.f,d4=0.f,d5=0.f,d6=0.f;
      #pragma unroll
      for (int ts=0;ts<4;++ts){
        int jg = mjm*64 + (tq*4+ts)*4 + jl;
        float rx = xi - px[jg] + a0;
        float ry = yi - py[jg] + a1c;
        float rz = zi - pz[jg] + a2c;
        float dsq = rx*rx+ry*ry+rz*rz;
        if (dsq > 0.0f && jg != i){
          float d = sqrtf(dsq);
          float invd = __fdividef(1.0f, d);
          float invd2 = invd*invd;
          float ad = AL_F*d;
          float ec = fast_erfcf(ad);
          float ex = __expf(-ad*ad);
          float qq = qi*pq[jg];
          float P  = -(K1_F*ex*invd + ec*invd2);
          float b1 = qq*P*invd;
          float bW = qq*invd*( K1_F*ex*(TWOA2_F + 3.0f*invd2)*invd + 3.0f*ec*invd2*invd2 );
          float w1=bW*rx*rx, w2=bW*rx*ry, w3=bW*rx*rz, w4=bW*ry*ry, w5=bW*ry*rz, w6=bW*rz*rz;
          c0+=b1; c1+=w1; c2+=w2; c3+=w3; c4+=w4; c5+=w5; c6+=w6;
          float mj_ = pm[jg];
          d0=fmaf(b1,mj_,d0); d1=fmaf(w1,mj_,d1); d2=fmaf(w2,mj_,d2);
          d3=fmaf(w3,mj_,d3); d4=fmaf(w4,mj_,d4); d5=fmaf(w5,mj_,d5); d6=fmaf(w6,mj_,d6);
        }
      }
      u0+=(double)c0; u1v+=(double)c1; u2v+=(double)c2; u3+=(double)c3;
      u4+=(double)c4; u5+=(double)c5; u6+=(double)c6;
      m0+=(double)d0; m1v+=(double)d1; m2v+=(double)d2; m3+=(double)d3;
      m4+=(double)d4; m5+=(double)d5; m6+=(double)d6;
    }
    #pragma unroll
    for (int m=1;m<4;m<<=1){
      u0+=__shfl_xor(u0,m); u1v+=__shfl_xor(u1v,m); u2v+=__shfl_xor(u2v,m);
      u3+=__shfl_xor(u3,m); u4+=__shfl_xor(u4,m); u5+=__shfl_xor(u5,m); u6+=__shfl_xor(u6,m);
      m0+=__shfl_xor(m0,m); m1v+=__shfl_xor(m1v,m); m2v+=__shfl_xor(m2v,m);
      m3+=__shfl_xor(m3,m); m4+=__shfl_xor(m4,m); m5+=__shfl_xor(m5,m); m6+=__shfl_xor(m6,m);
    }
    if (jl == 0){
      double* rr = red2m + il*21;
      rr[0]=msi*u0; rr[1]=msi*u1v; rr[2]=msi*u2v; rr[3]=msi*u3;
      rr[4]=msi*u4; rr[5]=msi*u5; rr[6]=msi*u6;
      rr[7]=m0; rr[8]=m1v; rr[9]=m2v; rr[10]=m3; rr[11]=m4; rr[12]=m5; rr[13]=m6;
      rr[14]=msi*m0; rr[15]=msi*m1v; rr[16]=msi*m2v; rr[17]=msi*m3;
      rr[18]=msi*m4; rr[19]=msi*m5; rr[20]=msi*m6;
    }
    __syncthreads();
    if (tid < 21){
      double s = 0.0;
      for (int u=0;u<64;++u) s += red2m[u*21+tid];
      redS[tid] = s;
    }
    __syncthreads();
    if (tid < 18){
      int slot = tid/6, e = tid%6;
      const double* S = redS + slot*7;
      double val;
      if (e==0) val = S[0] + S[1];
      else if (e==1) val = S[2];
      else if (e==2) val = S[3];
      else if (e==3) val = S[0] + S[4];
      else if (e==4) val = S[5];
      else val = S[0] + S[6];
      double sgn = (slot==2) ? -1.0 : 1.0;
      int tm0 = (slot==1) ? mjm : mi;
      int tm1 = (slot==0) ? mi : mjm;
      atomicAdd(&Mg[cp*96 + (tm0*4+tm1)*6 + e], sgn*2.0*KE_C*val);
    }
  } else if (b < KS_B + REG_B + REM_B + BO_B) {
    // =============== Born: gradient + energy + M ===========================
    int bb = b - (KS_B + REG_B + REM_B);
    int cp = bb & (NCPY-1);
    double* g = gN + cp*768;
    int p = bb*256 + tid;
    int ai = ii[p], aj = jj[p];
    double rx = posc(R,shiftv,im,film,aj,0) - posc(R,shiftv,im,film,ai,0) + (double)offs[p*3+0];
    double ry = posc(R,shiftv,im,film,aj,1) - posc(R,shiftv,im,film,ai,1) + (double)offs[p*3+1];
    double rz = posc(R,shiftv,im,film,aj,2) - posc(R,shiftv,im,film,ai,2) + (double)offs[p*3+2];
    double dsq = rx*rx + ry*ry + rz*rz;
    double d = sqrt(dsq);
    double y = 0.0;
    if (d < CUTOFF_C) {
      double qq = fabs((double)q[ai]*(double)q[aj]);
      int    ni = (int)(na[p] + 0.5f);
      double n  = (double)ni;
      double B  = qq * ipown((double)r0a[p], ni-1) / n;
      double dmn = ipown(1.0/d, ni);
      y = 0.5*KE_C*B*(dmn - ipown(1.0/CUTOFF_C, ni));
      double c = (-0.5*KE_C*n*B) * (dmn / dsq);
      atomicAdd(&g[aj*3+0],  c*rx);
      atomicAdd(&g[aj*3+1],  c*ry);
      atomicAdd(&g[aj*3+2],  c*rz);
      atomicAdd(&g[ai*3+0], -c*rx);
      atomicAdd(&g[ai*3+1], -c*ry);
      atomicAdd(&g[ai*3+2], -c*rz);
      // Hessian M
      bool fi = film[ai] > 0, fj = film[aj] > 0;
      if (fi || fj){
        double b2 = -c*(n+2.0)/dsq;
        double E0 = c + b2*rx*rx, E1 = b2*rx*ry, E2 = b2*rx*rz;
        double E3 = c + b2*ry*ry, E4 = b2*ry*rz, E5 = c + b2*rz*rz;
        double* M = Mg + cp*96;
        int mi_ = im[ai], mj_ = im[aj];
        if (fi){
          double* t = M + (mi_*4+mi_)*6;
          atomicAdd(&t[0],E0); atomicAdd(&t[1],E1); atomicAdd(&t[2],E2);
          atomicAdd(&t[3],E3); atomicAdd(&t[4],E4); atomicAdd(&t[5],E5);
        }
        if (fj){
          double* t = M + (mj_*4+mj_)*6;
          atomicAdd(&t[0],E0); atomicAdd(&t[1],E1); atomicAdd(&t[2],E2);
          atomicAdd(&t[3],E3); atomicAdd(&t[4],E4); atomicAdd(&t[5],E5);
        }
        if (fi && fj){
          if (mi_ != mj_){
            double* t = M + (mi_*4+mj_)*6;
            atomicAdd(&t[0],-E0); atomicAdd(&t[1],-E1); atomicAdd(&t[2],-E2);
            atomicAdd(&t[3],-E3); atomicAdd(&t[4],-E4); atomicAdd(&t[5],-E5);
            double* u = M + (mj_*4+mi_)*6;
            atomicAdd(&u[0],-E0); atomicAdd(&u[1],-E1); atomicAdd(&u[2],-E2);
            atomicAdd(&u[3],-E3); atomicAdd(&u[4],-E4); atomicAdd(&u[5],-E5);
          } else {
            double* t = M + (mi_*4+mi_)*6;
            atomicAdd(&t[0],-2.0*E0); atomicAdd(&t[1],-2.0*E1); atomicAdd(&t[2],-2.0*E2);
            atomicAdd(&t[3],-2.0*E3); atomicAdd(&t[4],-2.0*E4); atomicAdd(&t[5],-2.0*E5);
          }
        }
      }
    }
    {
      int myMol = im[ai];
      #pragma unroll
      for (int mm=0; mm<4; ++mm){
        double v = (myMol==mm) ? y : 0.0;
        for (int off=32; off; off>>=1) v += __shfl_down(v, off, 64);
        if ((tid & 63) == 0 && v != 0.0)
          atomicAdd(&scal[cp*8+3+mm], v);
      }
    }
  } else {
    // =============== S2: gradient + energy + M (zz only) ===================
    int jc = b - (KS_B + REG_B + REM_B + BO_B);
    int cp = (jc*2+1) & (NCPY-1);
    double* g = gN + cp*768;
    float *zz=f, *zq=f+32, *zm=f+64;
    if (tid < 32) {
      int j = jc*32 + tid;
      float4 p = posf4[j];
      zz[tid] = p.z; zq[tid] = p.w;
      zm[tid] = film[j] > 0 ? 1.0f : 0.0f;
    }
    __syncthreads();
    float4 pi = posf4[tid];
    float ziv = pi.z, qi = pi.w;
    double msi = film[tid] > 0 ? 1.0 : 0.0;
    int mi = tid >> 6, mjs2 = jc >> 1;
    double acc = 0.0, S2p = 0.0;
    double uii=0.0, ujj=0.0, uij=0.0;
    for (int j2=0;j2<32;++j2){
      int jg = jc*32 + j2;
      float z = ziv - zz[j2];
      float az = AL_F*z;
      float qq = qi*zq[j2];
      float ex = __expf(-az*az);
      float e = 1.0f - fast_erfcf(az);
      S2p += (double)(qq*(z*e + ex*IAS_F));
      acc += (double)(qq*e);
      if (jg != tid){
        double gpp = (double)(qq*K1_F*ex);
        double mj_ = (double)zm[j2];
        uii += msi*gpp;
        ujj += mj_*gpp;
        uij += msi*mj_*gpp;
      }
    }
    double area = cell_area(cell);
    atomicAdd(&g[tid*3+2], (-8.0*KE_C*PI_D/area)*acc);
    #pragma unroll
    for (int m=1;m<64;m<<=1){
      S2p += __shfl_xor(S2p, m);
      uii += __shfl_xor(uii, m); ujj += __shfl_xor(ujj, m); uij += __shfl_xor(uij, m);
    }
    if ((tid & 63) == 0){
      atomicAdd(&scal[cp*8+1], S2p);
      double Cs = -4.0*KE_C*PI_D/area;
      atomicAdd(&Mg[cp*96 + (mi*4+mi)*6 + 5],     Cs*uii);
      atomicAdd(&Mg[cp*96 + (mjs2*4+mjs2)*6 + 5], Cs*ujj);
      atomicAdd(&Mg[cp*96 + (mi*4+mjs2)*6 + 5],  -Cs*uij);
    }
  }
}

// ---------------- finish: energies, ffn, fng = -2 M ff (fully parallel) -----
__global__ void finish_kernel(const double* gN, const double* scal, const double* Mg,
                              const float* q, const float* cell, const int* im,
                              const int* film, float* out){
  __shared__ double gsh[768];
  __shared__ double ffsh[12];
  __shared__ double Msh[96];
  __shared__ double qred[256];
  __shared__ double ssum[7];
  __shared__ int    msk[256];
  int i = threadIdx.x;
  // parallel, coalesced: per-atom copy-sums + mask + q^2
  double s0=0,s1=0,s2v=0;
  for (int c=0;c<NCPY;++c){
    const double* g = gN + c*768;
    s0 += g[i*3+0]; s1 += g[i*3+1]; s2v += g[i*3+2];
  }
  gsh[i*3+0]=s0; gsh[i*3+1]=s1; gsh[i*3+2]=s2v;
  msk[i] = (film[i] > 0) ? im[i] : -1;
  { double qa = (double)q[i]; qred[i] = qa*qa; }
  if (i < 96){
    double s = 0.0;
    for (int c=0;c<NCPY;++c) s += Mg[c*96 + i];
    Msh[i] = s;
  }
  if (i < 7){
    double s = 0.0;
    for (int c=0;c<NCPY;++c) s += scal[c*8 + i];
    ssum[i] = s;
  }
  __syncthreads();
  // qs tree-reduce
  for (int o=128;o;o>>=1){ if (i<o) qred[i] += qred[i+o]; __syncthreads(); }
  // ffsh from LDS only
  if (i < 12) {
    int mm = i/3, c = i%3;
    double s = 0.0;
    for (int a = 0; a < N_ATOMS; ++a)
      if (msk[a] == mm) s -= gsh[a*3+c];
    ffsh[i] = s;
  }
  __syncthreads();
  if (i == 0) {
    double area = cell_area(cell);
    double S = ssum[0], S2 = ssum[1], RR = ssum[2];
    double recip = KE_C*PI_D*(S/(2.0*area) - S2/area);
    double realE = 0.5*KE_C*RR;
    double selfE = -ALPHA_C/sqrt(PI_D)*qred[0]*KE_C;
    double Ec = recip + realE + selfE;
    out[4] = (float)Ec;
    for (int m = 0; m < 4; ++m) {
      double yb = ssum[3+m];
      out[5+m] = (float)yb;
      out[m]   = (float)(Ec + yb);
    }
  }
  if (i < 4) {
    double f0 = ffsh[i*3+0], f1 = ffsh[i*3+1], f2 = ffsh[i*3+2];
    out[9+i] = (float)(f0*f0 + f1*f1 + f2*f2);
  }
  if (i < 12) {
    int m = i/3, c = i%3;
    const int sidx[3][3] = {{0,1,2},{1,3,4},{2,4,5}};
    double s = 0.0;
    for (int m2=0;m2<4;++m2)
      for (int c2=0;c2<3;++c2)
        s += Msh[(m*4+m2)*6 + sidx[c][c2]] * ffsh[m2*3+c2];
    out[13+i] = (float)(-2.0*s);
  }
}

extern "C" void kernel_launch(void* const* d_in, const int* in_sizes, int n_in,
                              void* d_out, int out_size, void* d_ws, size_t ws_size,
                              hipStream_t stream){
  const float* R      = (const float*)d_in[0];
  const float* shiftv = (const float*)d_in[1];
  const float* q      = (const float*)d_in[2];
  const float* offs   = (const float*)d_in[3];
  const float* cell   = (const float*)d_in[4];
  const float* recipc = (const float*)d_in[5];
  const float* r0a    = (const float*)d_in[6];
  const float* na     = (const float*)d_in[7];
  const int*   ii     = (const int*)d_in[8];
  const int*   jj     = (const int*)d_in[9];
  const int*   im     = (const int*)d_in[10];
  const int*   film   = (const int*)d_in[11];
  float* out = (float*)d_out;

  double* ws   = (double*)d_ws;
  double* scal = ws;                         // NCPY*8   = 128
  double* gN   = ws + NCPY*8;                // NCPY*768 = 12288
  double* Mg   = ws + NCPY*8 + NCPY*768;     // NCPY*96  = 1536
  float4* tab4  = (float4*)(ws + ZWORDS);    // 84*256 float4
  float4* posf4 = tab4 + 84*256;             // 256 float4

  hipLaunchKernelGGL(prep_kernel, dim3(NPREP), dim3(256), 0, stream,
                     R, shiftv, q, im, film, recipc, ws, tab4, posf4);
  hipLaunchKernelGGL(pass_kernel, dim3(NBLK), dim3(256), 0, stream,
                     R, shiftv, q, offs, cell, recipc, r0a, na, ii, jj, im, film,
                     tab4, posf4, gN, scal, Mg);
  hipLaunchKernelGGL(finish_kernel, dim3(1), dim3(256), 0, stream,
                     gN, scal, Mg, q, cell, im, film, out);
}